// Round 1
// baseline (379.839 us; speedup 1.0000x reference)
//
#include <hip/hip_runtime.h>
#include <cstddef>

// Problem constants (from reference): N=50000, Fin=128, H=C=64, E=800000.
constexpr int FIN = 128;

// ---------------------------------------------------------------------------
// Block-wide (256-thread) exclusive scan helper: wave shfl scan + LDS combine.
// ---------------------------------------------------------------------------
__device__ __forceinline__ int block_excl_scan_256(int v, int tid, int* wsums) {
    int lane = tid & 63, w = tid >> 6;
    int x = v;
#pragma unroll
    for (int off = 1; off < 64; off <<= 1) {
        int y = __shfl_up(x, off, 64);
        if (lane >= off) x += y;
    }
    if (lane == 63) wsums[w] = x;       // inclusive wave total
    __syncthreads();
    int add = 0;
#pragma unroll
    for (int i = 0; i < 4; ++i) add += (i < w) ? wsums[i] : 0;
    return x + add - v;                 // exclusive
}

// ---------------------------------------------------------------------------
// GEMM: H[N,64] = X[N,K] @ W[K,64]; fused AS[n]=H[n]·a_src, AD[n]=H[n]·a_dst.
// One wave per 4 nodes (N must be a multiple of 16 per block of 4 waves;
// 50000 = 3125*16). W transposed into LDS [64][K+4]: 16B-aligned rows,
// conflict-free ds_read_b128 (bank stride 4 over 8-lane service groups).
// ---------------------------------------------------------------------------
template <int K>
__global__ __launch_bounds__(256)
void gemm_feat(const float* __restrict__ X, const float* __restrict__ W,
               const float* __restrict__ ASRC, const float* __restrict__ ADST,
               float* __restrict__ H, float* __restrict__ AS,
               float* __restrict__ AD, int N) {
    constexpr int LDW = K + 4;
    __shared__ float Wl[64 * LDW];
    int tid = threadIdx.x;
    for (int idx = tid; idx < K * 64; idx += 256) {
        int k = idx >> 6, c = idx & 63;
        Wl[c * LDW + k] = W[idx];
    }
    __syncthreads();

    int lane = tid & 63;
    int wv = tid >> 6;
    int n0 = (blockIdx.x * 4 + wv) * 4;      // 4 nodes per wave
    if (n0 >= N) return;

    float asc = ASRC[lane], adc = ADST[lane];
    const float* wrow = Wl + lane * LDW;
    const float* x0 = X + (size_t)n0 * K;
    const float* x1 = x0 + K;
    const float* x2 = x1 + K;
    const float* x3 = x2 + K;

    float acc0 = 0.f, acc1 = 0.f, acc2 = 0.f, acc3 = 0.f;
#pragma unroll 4
    for (int k = 0; k < K; k += 4) {
        float4 wq = *(const float4*)(wrow + k);   // ds_read_b128
        float4 xa = *(const float4*)(x0 + k);     // wave-uniform 16B loads
        float4 xb = *(const float4*)(x1 + k);
        float4 xc = *(const float4*)(x2 + k);
        float4 xd = *(const float4*)(x3 + k);
        acc0 += xa.x * wq.x + xa.y * wq.y + xa.z * wq.z + xa.w * wq.w;
        acc1 += xb.x * wq.x + xb.y * wq.y + xb.z * wq.z + xb.w * wq.w;
        acc2 += xc.x * wq.x + xc.y * wq.y + xc.z * wq.z + xc.w * wq.w;
        acc3 += xd.x * wq.x + xd.y * wq.y + xd.z * wq.z + xd.w * wq.w;
    }

    H[(size_t)n0 * 64 + lane] = acc0;
    H[(size_t)(n0 + 1) * 64 + lane] = acc1;
    H[(size_t)(n0 + 2) * 64 + lane] = acc2;
    H[(size_t)(n0 + 3) * 64 + lane] = acc3;

    float va0 = acc0 * asc, vd0 = acc0 * adc;
    float va1 = acc1 * asc, vd1 = acc1 * adc;
    float va2 = acc2 * asc, vd2 = acc2 * adc;
    float va3 = acc3 * asc, vd3 = acc3 * adc;
#pragma unroll
    for (int off = 32; off > 0; off >>= 1) {
        va0 += __shfl_xor(va0, off, 64); vd0 += __shfl_xor(vd0, off, 64);
        va1 += __shfl_xor(va1, off, 64); vd1 += __shfl_xor(vd1, off, 64);
        va2 += __shfl_xor(va2, off, 64); vd2 += __shfl_xor(vd2, off, 64);
        va3 += __shfl_xor(va3, off, 64); vd3 += __shfl_xor(vd3, off, 64);
    }
    if (lane == 0) {
        AS[n0] = va0;     AD[n0] = vd0;
        AS[n0 + 1] = va1; AD[n0 + 1] = vd1;
        AS[n0 + 2] = va2; AD[n0 + 2] = vd2;
        AS[n0 + 3] = va3; AD[n0 + 3] = vd3;
    }
}

// ---------------------------------------------------------------------------
// CSR build: histogram over dst, 2-level exclusive scan, atomic slot scatter.
// ---------------------------------------------------------------------------
__global__ __launch_bounds__(256)
void hist_kernel(const int* __restrict__ dst, int E, int* __restrict__ deg) {
    int i = blockIdx.x * 256 + threadIdx.x;
    if (i < E) atomicAdd(&deg[dst[i]], 1);
}

__global__ __launch_bounds__(256)
void scan_sums(const int* __restrict__ deg, int N, int* __restrict__ bsum) {
    __shared__ int wsums[4];
    int tid = threadIdx.x;
    int i = blockIdx.x * 256 + tid;
    int x = (i < N) ? deg[i] : 0;
#pragma unroll
    for (int off = 32; off > 0; off >>= 1) x += __shfl_xor(x, off, 64);
    if ((tid & 63) == 0) wsums[tid >> 6] = x;
    __syncthreads();
    if (tid == 0) bsum[blockIdx.x] = wsums[0] + wsums[1] + wsums[2] + wsums[3];
}

__global__ __launch_bounds__(256)
void scan_partials(const int* __restrict__ bsum, int NB, int* __restrict__ boff) {
    __shared__ int wsums[4];
    int tid = threadIdx.x;
    int v = (tid < NB) ? bsum[tid] : 0;
    int e = block_excl_scan_256(v, tid, wsums);
    if (tid < NB) boff[tid] = e;
}

__global__ __launch_bounds__(256)
void scan_final(const int* __restrict__ deg, const int* __restrict__ boff,
                int N, int E, int* __restrict__ row_ptr, int* __restrict__ cursor) {
    __shared__ int wsums[4];
    int tid = threadIdx.x;
    int i = blockIdx.x * 256 + tid;
    int v = (i < N) ? deg[i] : 0;
    int e = block_excl_scan_256(v, tid, wsums);
    int o = boff[blockIdx.x] + e;
    if (i < N) { row_ptr[i] = o; cursor[i] = o; }
    if (i == 0) row_ptr[N] = E;
}

__global__ __launch_bounds__(256)
void scatter_kernel(const int* __restrict__ src, const int* __restrict__ dst,
                    int E, int* __restrict__ cursor, int* __restrict__ csr_src) {
    int i = blockIdx.x * 256 + threadIdx.x;
    if (i < E) {
        int p = atomicAdd(&cursor[dst[i]], 1);
        csr_src[p] = src[i];
    }
}

// ---------------------------------------------------------------------------
// GAT aggregate: one wave per dst node, lane = channel. Online softmax over
// incoming edges; src indices + leaky(e) loaded cooperatively 64 at a time,
// broadcast by shfl; next h-row prefetched to hide gather latency.
// ---------------------------------------------------------------------------
__global__ __launch_bounds__(256)
void gat_aggregate(const float* __restrict__ H, const float* __restrict__ AS,
                   const float* __restrict__ AD, const int* __restrict__ row_ptr,
                   const int* __restrict__ csr_src, const float* __restrict__ bias,
                   float* __restrict__ OUT, int N, int relu) {
    int lane = threadIdx.x & 63;
    int n = blockIdx.x * 4 + (threadIdx.x >> 6);
    if (n >= N) return;

    int base = row_ptr[n], end = row_ptr[n + 1];
    float adn = AD[n];
    float m = -INFINITY, s = 0.f, acc = 0.f;

    for (int c0 = base; c0 < end; c0 += 64) {
        int cnt = min(64, end - c0);
        int srcl = 0;
        float el = -INFINITY;
        if (lane < cnt) {
            srcl = csr_src[c0 + lane];          // coalesced
            float e = AS[srcl] + adn;           // random 4B gather (L2-hot)
            el = e > 0.f ? e : 0.2f * e;        // LeakyReLU(0.2)
        }
        int s0 = __shfl(srcl, 0, 64);
        float hv = H[(size_t)s0 * 64 + lane];   // prefetch edge 0
        for (int j = 0; j < cnt; ++j) {
            float e = __shfl(el, j, 64);
            float hcur = hv;
            if (j + 1 < cnt) {
                int sn = __shfl(srcl, j + 1, 64);
                hv = H[(size_t)sn * 64 + lane]; // prefetch next row
            }
            float mn = fmaxf(m, e);
            float sc = __expf(m - mn);          // exp(-inf)=0 on first edge
            float p = __expf(e - mn);
            s = s * sc + p;
            acc = acc * sc + p * hcur;
            m = mn;
        }
    }
    float o = acc / (s + 1e-16f) + bias[lane];
    if (relu) o = fmaxf(o, 0.f);
    OUT[(size_t)n * 64 + lane] = o;
}

// ---------------------------------------------------------------------------
extern "C" void kernel_launch(void* const* d_in, const int* in_sizes, int n_in,
                              void* d_out, int out_size, void* d_ws, size_t ws_size,
                              hipStream_t stream) {
    const float* x    = (const float*)d_in[0];
    const int*   ei   = (const int*)d_in[1];     // [2,E] int32
    const float* W1   = (const float*)d_in[2];
    const float* as1w = (const float*)d_in[3];
    const float* ad1w = (const float*)d_in[4];
    const float* b1   = (const float*)d_in[5];
    const float* W2   = (const float*)d_in[6];
    const float* as2w = (const float*)d_in[7];
    const float* ad2w = (const float*)d_in[8];
    const float* b2   = (const float*)d_in[9];
    float* out = (float*)d_out;

    const int N = in_sizes[0] / FIN;   // 50000
    const int E = in_sizes[1] / 2;     // 800000
    const int* esrc = ei;
    const int* edst = ei + E;

    // Workspace layout (all 4-byte elems; ~30 MB total)
    float* ws  = (float*)d_ws;
    float* h   = ws;                        // [N*64] h1, reused as h2
    float* r1  = h + (size_t)N * 64;        // [N*64] relu(layer1)
    float* AS1 = r1 + (size_t)N * 64;       // [N]
    float* AD1 = AS1 + N;
    float* AS2 = AD1 + N;
    float* AD2 = AS2 + N;
    int* deg     = (int*)(AD2 + N);         // [N]
    int* row_ptr = deg + N;                 // [N+1]
    int* cursor  = row_ptr + N + 1;         // [N]
    int* bsum    = cursor + N;              // [256]
    int* boff    = bsum + 256;              // [256]
    int* csr     = boff + 256;              // [E]

    hipMemsetAsync(deg, 0, (size_t)N * sizeof(int), stream);

    const int nbE = (E + 255) / 256;
    const int NB  = (N + 255) / 256;

    hipLaunchKernelGGL(hist_kernel, dim3(nbE), dim3(256), 0, stream, edst, E, deg);
    hipLaunchKernelGGL(scan_sums, dim3(NB), dim3(256), 0, stream, deg, N, bsum);
    hipLaunchKernelGGL(scan_partials, dim3(1), dim3(256), 0, stream, bsum, NB, boff);
    hipLaunchKernelGGL(scan_final, dim3(NB), dim3(256), 0, stream, deg, boff, N, E,
                       row_ptr, cursor);
    hipLaunchKernelGGL(scatter_kernel, dim3(nbE), dim3(256), 0, stream, esrc, edst,
                       E, cursor, csr);

    // Layer 1
    hipLaunchKernelGGL(gemm_feat<128>, dim3(N / 16), dim3(256), 0, stream,
                       x, W1, as1w, ad1w, h, AS1, AD1, N);
    hipLaunchKernelGGL(gat_aggregate, dim3(N / 4), dim3(256), 0, stream,
                       h, AS1, AD1, row_ptr, csr, b1, r1, N, 1);
    // Layer 2
    hipLaunchKernelGGL(gemm_feat<64>, dim3(N / 16), dim3(256), 0, stream,
                       r1, W2, as2w, ad2w, h, AS2, AD2, N);
    hipLaunchKernelGGL(gat_aggregate, dim3(N / 4), dim3(256), 0, stream,
                       h, AS2, AD2, row_ptr, csr, b2, out, N, 0);
}

// Round 2
// 285.130 us; speedup vs baseline: 1.3322x; 1.3322x over previous
//
#include <hip/hip_runtime.h>
#include <cstddef>

constexpr int FIN = 128;

// ---------------------------------------------------------------------------
// Block-wide (256-thread) exclusive scan helper: wave shfl scan + LDS combine.
// ---------------------------------------------------------------------------
__device__ __forceinline__ int block_excl_scan_256(int v, int tid, int* wsums) {
    int lane = tid & 63, w = tid >> 6;
    int x = v;
#pragma unroll
    for (int off = 1; off < 64; off <<= 1) {
        int y = __shfl_up(x, off, 64);
        if (lane >= off) x += y;
    }
    if (lane == 63) wsums[w] = x;
    __syncthreads();
    int add = 0;
#pragma unroll
    for (int i = 0; i < 4; ++i) add += (i < w) ? wsums[i] : 0;
    return x + add - v;
}

// ---------------------------------------------------------------------------
// GEMM: H[N,64] = X[N,K] @ W[K,64]; fused AS[n]=H[n]·a_src, AD[n]=H[n]·a_dst.
// Block = 256 thr = 64-node x 64-ch tile. X tile staged in LDS with row pad
// K+1 (lane bank stride 2 -> 2-way alias, free). W row-major [K][64] in LDS
// (b128 reads are 16/32-lane broadcasts, conflict-free). Thread computes a
// 2-node x 8-ch register tile: per k, 2 x-reads + 2 w-b128 + 16 FMA ->
// FMA-bound. Epilogue reduces AS/AD via shfl + cross-wave LDS.
// ---------------------------------------------------------------------------
template <int K>
__global__ __launch_bounds__(256)
void gemm_feat(const float* __restrict__ X, const float* __restrict__ W,
               const float* __restrict__ ASRC, const float* __restrict__ ADST,
               float* __restrict__ H, float* __restrict__ AS,
               float* __restrict__ AD, int N) {
    constexpr int LDX = K + 1;
    __shared__ float Xs[64 * LDX];
    __shared__ float Ws[K * 64];
    __shared__ float redS[4 * 64];
    __shared__ float redD[4 * 64];

    const int tid = threadIdx.x;
    const int nb = blockIdx.x * 64;

    // Stage W (coalesced, conflict-free)
    for (int idx = tid; idx < K * 64; idx += 256) Ws[idx] = W[idx];

    // Stage X tile rows nb..nb+63 (coalesced float4 global reads)
    constexpr int QPR = K / 4;
    for (int q = tid; q < 64 * QPR; q += 256) {
        int r = q / QPR, kq = q % QPR;
        float4 v = make_float4(0.f, 0.f, 0.f, 0.f);
        if (nb + r < N) v = *(const float4*)(X + (size_t)(nb + r) * K + 4 * kq);
        float* p = Xs + r * LDX + 4 * kq;
        p[0] = v.x; p[1] = v.y; p[2] = v.z; p[3] = v.w;
    }
    __syncthreads();

    const int l = tid & 63, w = tid >> 6;
    const int n0 = 2 * (l & 31);            // 2 nodes per thread
    const int c0 = 16 * w + 8 * (l >> 5);   // 8 channels per thread

    float acc[2][8];
#pragma unroll
    for (int i = 0; i < 2; ++i)
#pragma unroll
        for (int j = 0; j < 8; ++j) acc[i][j] = 0.f;

    const float* xr0 = Xs + n0 * LDX;
    const float* xr1 = xr0 + LDX;
    const float* wp = Ws + c0;

#pragma unroll 4
    for (int k = 0; k < K; ++k) {
        float4 wa = *(const float4*)(wp + k * 64);
        float4 wb = *(const float4*)(wp + k * 64 + 4);
        float x0 = xr0[k];
        float x1 = xr1[k];
        acc[0][0] += x0 * wa.x; acc[0][1] += x0 * wa.y;
        acc[0][2] += x0 * wa.z; acc[0][3] += x0 * wa.w;
        acc[0][4] += x0 * wb.x; acc[0][5] += x0 * wb.y;
        acc[0][6] += x0 * wb.z; acc[0][7] += x0 * wb.w;
        acc[1][0] += x1 * wa.x; acc[1][1] += x1 * wa.y;
        acc[1][2] += x1 * wa.z; acc[1][3] += x1 * wa.w;
        acc[1][4] += x1 * wb.x; acc[1][5] += x1 * wb.y;
        acc[1][6] += x1 * wb.z; acc[1][7] += x1 * wb.w;
    }

    // Store H rows (16B stores)
    if (nb + n0 < N) {
        float* hp = H + (size_t)(nb + n0) * 64 + c0;
        *(float4*)hp       = make_float4(acc[0][0], acc[0][1], acc[0][2], acc[0][3]);
        *(float4*)(hp + 4) = make_float4(acc[0][4], acc[0][5], acc[0][6], acc[0][7]);
    }
    if (nb + n0 + 1 < N) {
        float* hp = H + (size_t)(nb + n0 + 1) * 64 + c0;
        *(float4*)hp       = make_float4(acc[1][0], acc[1][1], acc[1][2], acc[1][3]);
        *(float4*)(hp + 4) = make_float4(acc[1][4], acc[1][5], acc[1][6], acc[1][7]);
    }

    // Fused alpha: per-thread partial dot over its 8 channels
    float pa0 = 0.f, pd0 = 0.f, pa1 = 0.f, pd1 = 0.f;
#pragma unroll
    for (int j = 0; j < 8; ++j) {
        float as = ASRC[c0 + j], ad = ADST[c0 + j];
        pa0 += acc[0][j] * as; pd0 += acc[0][j] * ad;
        pa1 += acc[1][j] * as; pd1 += acc[1][j] * ad;
    }
    // combine the two 8-ch halves (lanes l and l^32 share nodes)
    pa0 += __shfl_xor(pa0, 32, 64); pd0 += __shfl_xor(pd0, 32, 64);
    pa1 += __shfl_xor(pa1, 32, 64); pd1 += __shfl_xor(pd1, 32, 64);
    if (l < 32) {
        redS[w * 64 + n0] = pa0; redS[w * 64 + n0 + 1] = pa1;
        redD[w * 64 + n0] = pd0; redD[w * 64 + n0 + 1] = pd1;
    }
    __syncthreads();
    if (tid < 64 && nb + tid < N) {
        float s = redS[tid] + redS[64 + tid] + redS[128 + tid] + redS[192 + tid];
        float d = redD[tid] + redD[64 + tid] + redD[128 + tid] + redD[192 + tid];
        AS[nb + tid] = s; AD[nb + tid] = d;
    }
}

// ---------------------------------------------------------------------------
// CSR build: histogram over dst, 2-level exclusive scan, atomic slot scatter.
// ---------------------------------------------------------------------------
__global__ __launch_bounds__(256)
void hist_kernel(const int* __restrict__ dst, int E, int* __restrict__ deg) {
    int i = blockIdx.x * 256 + threadIdx.x;
    if (i < E) atomicAdd(&deg[dst[i]], 1);
}

__global__ __launch_bounds__(256)
void scan_sums(const int* __restrict__ deg, int N, int* __restrict__ bsum) {
    __shared__ int wsums[4];
    int tid = threadIdx.x;
    int i = blockIdx.x * 256 + tid;
    int x = (i < N) ? deg[i] : 0;
#pragma unroll
    for (int off = 32; off > 0; off >>= 1) x += __shfl_xor(x, off, 64);
    if ((tid & 63) == 0) wsums[tid >> 6] = x;
    __syncthreads();
    if (tid == 0) bsum[blockIdx.x] = wsums[0] + wsums[1] + wsums[2] + wsums[3];
}

__global__ __launch_bounds__(256)
void scan_partials(const int* __restrict__ bsum, int NB, int* __restrict__ boff) {
    __shared__ int wsums[4];
    int tid = threadIdx.x;
    int v = (tid < NB) ? bsum[tid] : 0;
    int e = block_excl_scan_256(v, tid, wsums);
    if (tid < NB) boff[tid] = e;
}

__global__ __launch_bounds__(256)
void scan_final(const int* __restrict__ deg, const int* __restrict__ boff,
                int N, int E, int* __restrict__ row_ptr, int* __restrict__ cursor) {
    __shared__ int wsums[4];
    int tid = threadIdx.x;
    int i = blockIdx.x * 256 + tid;
    int v = (i < N) ? deg[i] : 0;
    int e = block_excl_scan_256(v, tid, wsums);
    int o = boff[blockIdx.x] + e;
    if (i < N) { row_ptr[i] = o; cursor[i] = o; }
    if (i == 0) row_ptr[N] = E;
}

__global__ __launch_bounds__(256)
void scatter_kernel(const int* __restrict__ src, const int* __restrict__ dst,
                    int E, int* __restrict__ cursor, int* __restrict__ csr_src) {
    int i = blockIdx.x * 256 + threadIdx.x;
    if (i < E) {
        int p = atomicAdd(&cursor[dst[i]], 1);
        csr_src[p] = src[i];
    }
}

// ---------------------------------------------------------------------------
// Fused softmax + aggregate: one wave per dst node, lane = channel.
// Fast path (deg<=64): lane-parallel e gather, shfl-xor max & sum reductions,
// then a 4-deep-pipelined accumulate over edges (4 independent accumulators,
// 4 H-row gathers in flight). Slow path (deg>64, rare) = chunked 2-phase.
// ---------------------------------------------------------------------------
__global__ __launch_bounds__(256)
void gat_aggregate(const float* __restrict__ H, const float* __restrict__ AS,
                   const float* __restrict__ AD, const int* __restrict__ row_ptr,
                   const int* __restrict__ csr_src, const float* __restrict__ bias,
                   float* __restrict__ OUT, int N, int relu) {
    const int lane = threadIdx.x & 63;
    const int n = blockIdx.x * 4 + (threadIdx.x >> 6);
    if (n >= N) return;

    const int base = row_ptr[n], end = row_ptr[n + 1];
    const int cnt = end - base;
    const float adn = AD[n];
    float out;

    if (cnt <= 64) {
        int srcl = 0;
        float el = -INFINITY;
        if (lane < cnt) {
            srcl = csr_src[base + lane];          // coalesced
            float e = AS[srcl] + adn;             // 4B gather (L2-hot)
            el = e > 0.f ? e : 0.2f * e;          // LeakyReLU(0.2)
        }
        float m = el;
#pragma unroll
        for (int off = 32; off > 0; off >>= 1) m = fmaxf(m, __shfl_xor(m, off, 64));
        float p = (lane < cnt) ? __expf(el - m) : 0.f;
        float s = p;
#pragma unroll
        for (int off = 32; off > 0; off >>= 1) s += __shfl_xor(s, off, 64);
        float al = p * (1.f / (s + 1e-16f));      // normalized alpha per lane-edge

        float acc0 = 0.f, acc1 = 0.f, acc2 = 0.f, acc3 = 0.f;
        int j = 0;
        for (; j + 4 <= cnt; j += 4) {
            int s0 = __shfl(srcl, j, 64),     s1 = __shfl(srcl, j + 1, 64);
            int s2 = __shfl(srcl, j + 2, 64), s3 = __shfl(srcl, j + 3, 64);
            float h0 = H[(size_t)s0 * 64 + lane];   // 4 gathers in flight
            float h1 = H[(size_t)s1 * 64 + lane];
            float h2 = H[(size_t)s2 * 64 + lane];
            float h3 = H[(size_t)s3 * 64 + lane];
            acc0 += __shfl(al, j, 64) * h0;
            acc1 += __shfl(al, j + 1, 64) * h1;
            acc2 += __shfl(al, j + 2, 64) * h2;
            acc3 += __shfl(al, j + 3, 64) * h3;
        }
        for (; j < cnt; ++j)
            acc0 += __shfl(al, j, 64) * H[(size_t)__shfl(srcl, j, 64) * 64 + lane];
        out = (acc0 + acc1) + (acc2 + acc3);
    } else {
        // pass 1: global max
        float m = -INFINITY;
        for (int c0 = base; c0 < end; c0 += 64) {
            int c = min(64, end - c0);
            float e = -INFINITY;
            if (lane < c) {
                int sr = csr_src[c0 + lane];
                float t = AS[sr] + adn;
                e = t > 0.f ? t : 0.2f * t;
            }
#pragma unroll
            for (int off = 32; off > 0; off >>= 1) e = fmaxf(e, __shfl_xor(e, off, 64));
            m = fmaxf(m, e);
        }
        // pass 2: sum + unnormalized accumulate
        float s = 0.f, acc = 0.f;
        for (int c0 = base; c0 < end; c0 += 64) {
            int c = min(64, end - c0);
            int srcl = 0;
            float p = 0.f;
            if (lane < c) {
                srcl = csr_src[c0 + lane];
                float t = AS[srcl] + adn;
                t = t > 0.f ? t : 0.2f * t;
                p = __expf(t - m);
            }
            float cs = p;
#pragma unroll
            for (int off = 32; off > 0; off >>= 1) cs += __shfl_xor(cs, off, 64);
            s += cs;
            for (int j = 0; j < c; ++j)
                acc += __shfl(p, j, 64) * H[(size_t)__shfl(srcl, j, 64) * 64 + lane];
        }
        out = acc * (1.f / (s + 1e-16f));
    }

    out += bias[lane];
    if (relu) out = fmaxf(out, 0.f);
    OUT[(size_t)n * 64 + lane] = out;
}

// ---------------------------------------------------------------------------
extern "C" void kernel_launch(void* const* d_in, const int* in_sizes, int n_in,
                              void* d_out, int out_size, void* d_ws, size_t ws_size,
                              hipStream_t stream) {
    const float* x    = (const float*)d_in[0];
    const int*   ei   = (const int*)d_in[1];
    const float* W1   = (const float*)d_in[2];
    const float* as1w = (const float*)d_in[3];
    const float* ad1w = (const float*)d_in[4];
    const float* b1   = (const float*)d_in[5];
    const float* W2   = (const float*)d_in[6];
    const float* as2w = (const float*)d_in[7];
    const float* ad2w = (const float*)d_in[8];
    const float* b2   = (const float*)d_in[9];
    float* out = (float*)d_out;

    const int N = in_sizes[0] / FIN;   // 50000
    const int E = in_sizes[1] / 2;     // 800000
    const int* esrc = ei;
    const int* edst = ei + E;

    float* ws  = (float*)d_ws;
    float* h   = ws;                        // [N*64]
    float* r1  = h + (size_t)N * 64;        // [N*64]
    float* AS1 = r1 + (size_t)N * 64;       // [N]
    float* AD1 = AS1 + N;
    float* AS2 = AD1 + N;
    float* AD2 = AS2 + N;
    int* deg     = (int*)(AD2 + N);
    int* row_ptr = deg + N;
    int* cursor  = row_ptr + N + 1;
    int* bsum    = cursor + N;
    int* boff    = bsum + 256;
    int* csr     = boff + 256;              // [E]

    hipMemsetAsync(deg, 0, (size_t)N * sizeof(int), stream);

    const int nbE = (E + 255) / 256;
    const int NB  = (N + 255) / 256;
    const int nbG = (N + 63) / 64;

    hipLaunchKernelGGL(hist_kernel, dim3(nbE), dim3(256), 0, stream, edst, E, deg);
    hipLaunchKernelGGL(scan_sums, dim3(NB), dim3(256), 0, stream, deg, N, bsum);
    hipLaunchKernelGGL(scan_partials, dim3(1), dim3(256), 0, stream, bsum, NB, boff);
    hipLaunchKernelGGL(scan_final, dim3(NB), dim3(256), 0, stream, deg, boff, N, E,
                       row_ptr, cursor);
    hipLaunchKernelGGL(scatter_kernel, dim3(nbE), dim3(256), 0, stream, esrc, edst,
                       E, cursor, csr);

    // Layer 1
    hipLaunchKernelGGL(gemm_feat<128>, dim3(nbG), dim3(256), 0, stream,
                       x, W1, as1w, ad1w, h, AS1, AD1, N);
    hipLaunchKernelGGL(gat_aggregate, dim3((N + 3) / 4), dim3(256), 0, stream,
                       h, AS1, AD1, row_ptr, csr, b1, r1, N, 1);
    // Layer 2
    hipLaunchKernelGGL(gemm_feat<64>, dim3(nbG), dim3(256), 0, stream,
                       r1, W2, as2w, ad2w, h, AS2, AD2, N);
    hipLaunchKernelGGL(gat_aggregate, dim3((N + 3) / 4), dim3(256), 0, stream,
                       h, AS2, AD2, row_ptr, csr, b2, out, N, 0);
}

// Round 3
// 228.876 us; speedup vs baseline: 1.6596x; 1.2458x over previous
//
#include <hip/hip_runtime.h>
#include <cstddef>

constexpr int FIN = 128;
constexpr int EPB = 4096;   // edges per block in bucket passes
constexpr int BSH = 7;      // bucket shift: 128 nodes per bucket
constexpr int NPB = 128;    // nodes per bucket

// ---------------------------------------------------------------------------
// Block-wide (256-thread) exclusive scan helper: wave shfl scan + LDS combine.
// ---------------------------------------------------------------------------
__device__ __forceinline__ int block_excl_scan_256(int v, int tid, int* wsums) {
    int lane = tid & 63, w = tid >> 6;
    int x = v;
#pragma unroll
    for (int off = 1; off < 64; off <<= 1) {
        int y = __shfl_up(x, off, 64);
        if (lane >= off) x += y;
    }
    if (lane == 63) wsums[w] = x;
    __syncthreads();
    int add = 0;
#pragma unroll
    for (int i = 0; i < 4; ++i) add += (i < w) ? wsums[i] : 0;
    return x + add - v;
}

// ---------------------------------------------------------------------------
// GEMM: H[N,64] = X[N,K] @ W[K,64]; fused AS[n]=H[n]·a_src, AD[n]=H[n]·a_dst.
// ---------------------------------------------------------------------------
template <int K>
__global__ __launch_bounds__(256)
void gemm_feat(const float* __restrict__ X, const float* __restrict__ W,
               const float* __restrict__ ASRC, const float* __restrict__ ADST,
               float* __restrict__ H, float* __restrict__ AS,
               float* __restrict__ AD, int N) {
    constexpr int LDX = K + 1;
    __shared__ float Xs[64 * LDX];
    __shared__ float Ws[K * 64];
    __shared__ float redS[4 * 64];
    __shared__ float redD[4 * 64];

    const int tid = threadIdx.x;
    const int nb = blockIdx.x * 64;

    for (int idx = tid; idx < K * 64; idx += 256) Ws[idx] = W[idx];

    constexpr int QPR = K / 4;
    for (int q = tid; q < 64 * QPR; q += 256) {
        int r = q / QPR, kq = q % QPR;
        float4 v = make_float4(0.f, 0.f, 0.f, 0.f);
        if (nb + r < N) v = *(const float4*)(X + (size_t)(nb + r) * K + 4 * kq);
        float* p = Xs + r * LDX + 4 * kq;
        p[0] = v.x; p[1] = v.y; p[2] = v.z; p[3] = v.w;
    }
    __syncthreads();

    const int l = tid & 63, w = tid >> 6;
    const int n0 = 2 * (l & 31);
    const int c0 = 16 * w + 8 * (l >> 5);

    float acc[2][8];
#pragma unroll
    for (int i = 0; i < 2; ++i)
#pragma unroll
        for (int j = 0; j < 8; ++j) acc[i][j] = 0.f;

    const float* xr0 = Xs + n0 * LDX;
    const float* xr1 = xr0 + LDX;
    const float* wp = Ws + c0;

#pragma unroll 4
    for (int k = 0; k < K; ++k) {
        float4 wa = *(const float4*)(wp + k * 64);
        float4 wb = *(const float4*)(wp + k * 64 + 4);
        float x0 = xr0[k];
        float x1 = xr1[k];
        acc[0][0] += x0 * wa.x; acc[0][1] += x0 * wa.y;
        acc[0][2] += x0 * wa.z; acc[0][3] += x0 * wa.w;
        acc[0][4] += x0 * wb.x; acc[0][5] += x0 * wb.y;
        acc[0][6] += x0 * wb.z; acc[0][7] += x0 * wb.w;
        acc[1][0] += x1 * wa.x; acc[1][1] += x1 * wa.y;
        acc[1][2] += x1 * wa.z; acc[1][3] += x1 * wa.w;
        acc[1][4] += x1 * wb.x; acc[1][5] += x1 * wb.y;
        acc[1][6] += x1 * wb.z; acc[1][7] += x1 * wb.w;
    }

    if (nb + n0 < N) {
        float* hp = H + (size_t)(nb + n0) * 64 + c0;
        *(float4*)hp       = make_float4(acc[0][0], acc[0][1], acc[0][2], acc[0][3]);
        *(float4*)(hp + 4) = make_float4(acc[0][4], acc[0][5], acc[0][6], acc[0][7]);
    }
    if (nb + n0 + 1 < N) {
        float* hp = H + (size_t)(nb + n0 + 1) * 64 + c0;
        *(float4*)hp       = make_float4(acc[1][0], acc[1][1], acc[1][2], acc[1][3]);
        *(float4*)(hp + 4) = make_float4(acc[1][4], acc[1][5], acc[1][6], acc[1][7]);
    }

    float pa0 = 0.f, pd0 = 0.f, pa1 = 0.f, pd1 = 0.f;
#pragma unroll
    for (int j = 0; j < 8; ++j) {
        float as = ASRC[c0 + j], ad = ADST[c0 + j];
        pa0 += acc[0][j] * as; pd0 += acc[0][j] * ad;
        pa1 += acc[1][j] * as; pd1 += acc[1][j] * ad;
    }
    pa0 += __shfl_xor(pa0, 32, 64); pd0 += __shfl_xor(pd0, 32, 64);
    pa1 += __shfl_xor(pa1, 32, 64); pd1 += __shfl_xor(pd1, 32, 64);
    if (l < 32) {
        redS[w * 64 + n0] = pa0; redS[w * 64 + n0 + 1] = pa1;
        redD[w * 64 + n0] = pd0; redD[w * 64 + n0 + 1] = pd1;
    }
    __syncthreads();
    if (tid < 64 && nb + tid < N) {
        float s = redS[tid] + redS[64 + tid] + redS[128 + tid] + redS[192 + tid];
        float d = redD[tid] + redD[64 + tid] + redD[128 + tid] + redD[192 + tid];
        AS[nb + tid] = s; AD[nb + tid] = d;
    }
}

// ---------------------------------------------------------------------------
// CSR build via two-level counting sort (all atomics in LDS, writes packed).
// ---------------------------------------------------------------------------
__global__ __launch_bounds__(256)
void bucket_count(const int* __restrict__ dst, int E, int nbuckp,
                  int* __restrict__ cnts) {
    __shared__ int hist[512];
    int tid = threadIdx.x;
    for (int i = tid; i < nbuckp; i += 256) hist[i] = 0;
    __syncthreads();
    int e0 = blockIdx.x * EPB;
    int e1 = min(e0 + EPB, E);
    for (int e = e0 + tid; e < e1; e += 256)
        atomicAdd(&hist[dst[e] >> BSH], 1);
    __syncthreads();
    for (int i = tid; i < nbuckp; i += 256)
        cnts[blockIdx.x * nbuckp + i] = hist[i];
}

// One block per bucket: exclusive scan down the block column; cnts becomes
// per-(block,bucket) offsets; btotal[b] = column total. Requires nblk < 256.
__global__ __launch_bounds__(256)
void bucket_colscan(int* __restrict__ cnts, int nblk, int nbuckp,
                    int* __restrict__ btotal) {
    __shared__ int wsums[4];
    int b = blockIdx.x;
    int tid = threadIdx.x;
    int v = (tid < nblk) ? cnts[tid * nbuckp + b] : 0;
    int excl = block_excl_scan_256(v, tid, wsums);
    if (tid < nblk) cnts[tid * nbuckp + b] = excl;
    if (tid == nblk) btotal[b] = excl;     // v=0 here -> excl == column total
}

// Single block of 512: exclusive scan of bucket totals -> bbase[0..nbuck].
__global__ __launch_bounds__(512)
void bucket_base_scan(const int* __restrict__ btotal, int nbuck,
                      int* __restrict__ bbase) {
    __shared__ int wsums[8];
    int tid = threadIdx.x;
    int lane = tid & 63, w = tid >> 6;
    int v = (tid < nbuck) ? btotal[tid] : 0;
    int x = v;
#pragma unroll
    for (int off = 1; off < 64; off <<= 1) {
        int y = __shfl_up(x, off, 64);
        if (lane >= off) x += y;
    }
    if (lane == 63) wsums[w] = x;
    __syncthreads();
    int add = 0;
#pragma unroll
    for (int i = 0; i < 8; ++i) add += (i < w) ? wsums[i] : 0;
    int excl = x + add - v;
    if (tid <= nbuck) bbase[tid] = excl;   // bbase[nbuck] == E
}

__global__ __launch_bounds__(256)
void bucket_scatter(const int* __restrict__ src, const int* __restrict__ dst,
                    int E, int nbuckp, const int* __restrict__ cnts,
                    const int* __restrict__ bbase, int2* __restrict__ ebuck) {
    __shared__ int cur[512];
    int tid = threadIdx.x;
    for (int i = tid; i < nbuckp; i += 256)
        cur[i] = bbase[i] + cnts[blockIdx.x * nbuckp + i];
    __syncthreads();
    int e0 = blockIdx.x * EPB;
    int e1 = min(e0 + EPB, E);
    for (int e = e0 + tid; e < e1; e += 256) {
        int d = dst[e];
        int p = atomicAdd(&cur[d >> BSH], 1);     // LDS atomic
        ebuck[p] = make_int2(src[e], d);          // bucket-contiguous 8B write
    }
}

// One block per bucket: per-node hist + scan -> row_ptr; LDS-cursor scatter
// into the bucket's contiguous CSR slice (all dirty lines fully packed).
__global__ __launch_bounds__(256)
void bucket_to_csr(const int2* __restrict__ ebuck, const int* __restrict__ bbase,
                   int N, int E, int* __restrict__ row_ptr,
                   int* __restrict__ csr_src) {
    __shared__ int hist[NPB];
    __shared__ int cur[NPB];
    __shared__ int wsums[4];
    int b = blockIdx.x, tid = threadIdx.x;
    int nstart = b << BSH;
    int base = bbase[b], endp = bbase[b + 1];
    if (tid < NPB) hist[tid] = 0;
    __syncthreads();
    for (int e = base + tid; e < endp; e += 256)
        atomicAdd(&hist[ebuck[e].y - nstart], 1);
    __syncthreads();
    int v = (tid < NPB) ? hist[tid] : 0;
    int excl = block_excl_scan_256(v, tid, wsums);
    if (tid < NPB) {
        cur[tid] = excl;
        if (nstart + tid < N) row_ptr[nstart + tid] = base + excl;
    }
    if (b == 0 && tid == 0) row_ptr[N] = E;
    __syncthreads();
    for (int e = base + tid; e < endp; e += 256) {
        int2 ed = ebuck[e];
        int p = atomicAdd(&cur[ed.y - nstart], 1);
        csr_src[base + p] = ed.x;
    }
}

// ---------------------------------------------------------------------------
// Fused softmax + aggregate: one wave per dst node, lane = channel.
// ---------------------------------------------------------------------------
__global__ __launch_bounds__(256)
void gat_aggregate(const float* __restrict__ H, const float* __restrict__ AS,
                   const float* __restrict__ AD, const int* __restrict__ row_ptr,
                   const int* __restrict__ csr_src, const float* __restrict__ bias,
                   float* __restrict__ OUT, int N, int relu) {
    const int lane = threadIdx.x & 63;
    const int n = blockIdx.x * 4 + (threadIdx.x >> 6);
    if (n >= N) return;

    const int base = row_ptr[n], end = row_ptr[n + 1];
    const int cnt = end - base;
    const float adn = AD[n];
    float out;

    if (cnt <= 64) {
        int srcl = 0;
        float el = -INFINITY;
        if (lane < cnt) {
            srcl = csr_src[base + lane];
            float e = AS[srcl] + adn;
            el = e > 0.f ? e : 0.2f * e;
        }
        float m = el;
#pragma unroll
        for (int off = 32; off > 0; off >>= 1) m = fmaxf(m, __shfl_xor(m, off, 64));
        float p = (lane < cnt) ? __expf(el - m) : 0.f;
        float s = p;
#pragma unroll
        for (int off = 32; off > 0; off >>= 1) s += __shfl_xor(s, off, 64);
        float al = p * (1.f / (s + 1e-16f));

        float acc0 = 0.f, acc1 = 0.f, acc2 = 0.f, acc3 = 0.f;
        int j = 0;
        for (; j + 4 <= cnt; j += 4) {
            int s0 = __shfl(srcl, j, 64),     s1 = __shfl(srcl, j + 1, 64);
            int s2 = __shfl(srcl, j + 2, 64), s3 = __shfl(srcl, j + 3, 64);
            float h0 = H[(size_t)s0 * 64 + lane];
            float h1 = H[(size_t)s1 * 64 + lane];
            float h2 = H[(size_t)s2 * 64 + lane];
            float h3 = H[(size_t)s3 * 64 + lane];
            acc0 += __shfl(al, j, 64) * h0;
            acc1 += __shfl(al, j + 1, 64) * h1;
            acc2 += __shfl(al, j + 2, 64) * h2;
            acc3 += __shfl(al, j + 3, 64) * h3;
        }
        for (; j < cnt; ++j)
            acc0 += __shfl(al, j, 64) * H[(size_t)__shfl(srcl, j, 64) * 64 + lane];
        out = (acc0 + acc1) + (acc2 + acc3);
    } else {
        float m = -INFINITY;
        for (int c0 = base; c0 < end; c0 += 64) {
            int c = min(64, end - c0);
            float e = -INFINITY;
            if (lane < c) {
                int sr = csr_src[c0 + lane];
                float t = AS[sr] + adn;
                e = t > 0.f ? t : 0.2f * t;
            }
#pragma unroll
            for (int off = 32; off > 0; off >>= 1) e = fmaxf(e, __shfl_xor(e, off, 64));
            m = fmaxf(m, e);
        }
        float s = 0.f, acc = 0.f;
        for (int c0 = base; c0 < end; c0 += 64) {
            int c = min(64, end - c0);
            int srcl = 0;
            float p = 0.f;
            if (lane < c) {
                srcl = csr_src[c0 + lane];
                float t = AS[srcl] + adn;
                t = t > 0.f ? t : 0.2f * t;
                p = __expf(t - m);
            }
            float cs = p;
#pragma unroll
            for (int off = 32; off > 0; off >>= 1) cs += __shfl_xor(cs, off, 64);
            s += cs;
            for (int j = 0; j < c; ++j)
                acc += __shfl(p, j, 64) * H[(size_t)__shfl(srcl, j, 64) * 64 + lane];
        }
        out = acc * (1.f / (s + 1e-16f));
    }

    out += bias[lane];
    if (relu) out = fmaxf(out, 0.f);
    OUT[(size_t)n * 64 + lane] = out;
}

// ---------------------------------------------------------------------------
extern "C" void kernel_launch(void* const* d_in, const int* in_sizes, int n_in,
                              void* d_out, int out_size, void* d_ws, size_t ws_size,
                              hipStream_t stream) {
    const float* x    = (const float*)d_in[0];
    const int*   ei   = (const int*)d_in[1];
    const float* W1   = (const float*)d_in[2];
    const float* as1w = (const float*)d_in[3];
    const float* ad1w = (const float*)d_in[4];
    const float* b1   = (const float*)d_in[5];
    const float* W2   = (const float*)d_in[6];
    const float* as2w = (const float*)d_in[7];
    const float* ad2w = (const float*)d_in[8];
    const float* b2   = (const float*)d_in[9];
    float* out = (float*)d_out;

    const int N = in_sizes[0] / FIN;   // 50000
    const int E = in_sizes[1] / 2;     // 800000
    const int* esrc = ei;
    const int* edst = ei + E;

    const int nbuck = (N + NPB - 1) >> BSH;      // 391 (must be <= 512)
    const int nbuckp = nbuck;
    const int nblk = (E + EPB - 1) / EPB;        // 196 (must be < 256)

    // Persistent workspace
    float* ws  = (float*)d_ws;
    float* h   = ws;                        // [N*64]
    float* r1  = h + (size_t)N * 64;        // [N*64]
    float* AS1 = r1 + (size_t)N * 64;       // [N]
    float* AD1 = AS1 + N;
    float* AS2 = AD1 + N;
    float* AD2 = AS2 + N;
    int* row_ptr = (int*)(AD2 + N);         // [N+1]
    int* csr     = row_ptr + N + 1;         // [E]

    // CSR-build temporaries alias h / r1 (dead once gemm_feat<128> runs)
    int2* ebuck  = (int2*)h;                // [E] int2 (needs 2E <= N*64 ints)
    int* cnts    = (int*)r1;                // [nblk*nbuckp]
    int* btotal  = cnts + nblk * nbuckp;    // [nbuck]
    int* bbase   = btotal + nbuck;          // [nbuck+1]

    hipLaunchKernelGGL(bucket_count, dim3(nblk), dim3(256), 0, stream,
                       edst, E, nbuckp, cnts);
    hipLaunchKernelGGL(bucket_colscan, dim3(nbuck), dim3(256), 0, stream,
                       cnts, nblk, nbuckp, btotal);
    hipLaunchKernelGGL(bucket_base_scan, dim3(1), dim3(512), 0, stream,
                       btotal, nbuck, bbase);
    hipLaunchKernelGGL(bucket_scatter, dim3(nblk), dim3(256), 0, stream,
                       esrc, edst, E, nbuckp, cnts, bbase, ebuck);
    hipLaunchKernelGGL(bucket_to_csr, dim3(nbuck), dim3(256), 0, stream,
                       ebuck, bbase, N, E, row_ptr, csr);

    // Layer 1
    const int nbG = (N + 63) / 64;
    hipLaunchKernelGGL(gemm_feat<128>, dim3(nbG), dim3(256), 0, stream,
                       x, W1, as1w, ad1w, h, AS1, AD1, N);
    hipLaunchKernelGGL(gat_aggregate, dim3((N + 3) / 4), dim3(256), 0, stream,
                       h, AS1, AD1, row_ptr, csr, b1, r1, N, 1);
    // Layer 2
    hipLaunchKernelGGL(gemm_feat<64>, dim3(nbG), dim3(256), 0, stream,
                       r1, W2, as2w, ad2w, h, AS2, AD2, N);
    hipLaunchKernelGGL(gat_aggregate, dim3((N + 3) / 4), dim3(256), 0, stream,
                       h, AS2, AD2, row_ptr, csr, b2, out, N, 0);
}

// Round 4
// 228.112 us; speedup vs baseline: 1.6651x; 1.0034x over previous
//
#include <hip/hip_runtime.h>
#include <cstddef>

constexpr int FIN = 128;
constexpr int EPB = 4096;   // edges per block in bucket passes
constexpr int BSH = 7;      // bucket shift: 128 nodes per bucket
constexpr int NPB = 128;    // nodes per bucket

// ---------------------------------------------------------------------------
// Block-wide (256-thread) exclusive scan helper: wave shfl scan + LDS combine.
// ---------------------------------------------------------------------------
__device__ __forceinline__ int block_excl_scan_256(int v, int tid, int* wsums) {
    int lane = tid & 63, w = tid >> 6;
    int x = v;
#pragma unroll
    for (int off = 1; off < 64; off <<= 1) {
        int y = __shfl_up(x, off, 64);
        if (lane >= off) x += y;
    }
    if (lane == 63) wsums[w] = x;
    __syncthreads();
    int add = 0;
#pragma unroll
    for (int i = 0; i < 4; ++i) add += (i < w) ? wsums[i] : 0;
    return x + add - v;
}

// ---------------------------------------------------------------------------
// GEMM: H[N,64] = X[N,K] @ W[K,64]; fused AS[n]=H[n]·a_src, AD[n]=H[n]·a_dst.
// ---------------------------------------------------------------------------
template <int K>
__global__ __launch_bounds__(256)
void gemm_feat(const float* __restrict__ X, const float* __restrict__ W,
               const float* __restrict__ ASRC, const float* __restrict__ ADST,
               float* __restrict__ H, float* __restrict__ AS,
               float* __restrict__ AD, int N) {
    constexpr int LDX = K + 1;
    __shared__ float Xs[64 * LDX];
    __shared__ float Ws[K * 64];
    __shared__ float redS[4 * 64];
    __shared__ float redD[4 * 64];

    const int tid = threadIdx.x;
    const int nb = blockIdx.x * 64;

    for (int idx = tid; idx < K * 64; idx += 256) Ws[idx] = W[idx];

    constexpr int QPR = K / 4;
    for (int q = tid; q < 64 * QPR; q += 256) {
        int r = q / QPR, kq = q % QPR;
        float4 v = make_float4(0.f, 0.f, 0.f, 0.f);
        if (nb + r < N) v = *(const float4*)(X + (size_t)(nb + r) * K + 4 * kq);
        float* p = Xs + r * LDX + 4 * kq;
        p[0] = v.x; p[1] = v.y; p[2] = v.z; p[3] = v.w;
    }
    __syncthreads();

    const int l = tid & 63, w = tid >> 6;
    const int n0 = 2 * (l & 31);
    const int c0 = 16 * w + 8 * (l >> 5);

    float acc[2][8];
#pragma unroll
    for (int i = 0; i < 2; ++i)
#pragma unroll
        for (int j = 0; j < 8; ++j) acc[i][j] = 0.f;

    const float* xr0 = Xs + n0 * LDX;
    const float* xr1 = xr0 + LDX;
    const float* wp = Ws + c0;

#pragma unroll 4
    for (int k = 0; k < K; ++k) {
        float4 wa = *(const float4*)(wp + k * 64);
        float4 wb = *(const float4*)(wp + k * 64 + 4);
        float x0 = xr0[k];
        float x1 = xr1[k];
        acc[0][0] += x0 * wa.x; acc[0][1] += x0 * wa.y;
        acc[0][2] += x0 * wa.z; acc[0][3] += x0 * wa.w;
        acc[0][4] += x0 * wb.x; acc[0][5] += x0 * wb.y;
        acc[0][6] += x0 * wb.z; acc[0][7] += x0 * wb.w;
        acc[1][0] += x1 * wa.x; acc[1][1] += x1 * wa.y;
        acc[1][2] += x1 * wa.z; acc[1][3] += x1 * wa.w;
        acc[1][4] += x1 * wb.x; acc[1][5] += x1 * wb.y;
        acc[1][6] += x1 * wb.z; acc[1][7] += x1 * wb.w;
    }

    if (nb + n0 < N) {
        float* hp = H + (size_t)(nb + n0) * 64 + c0;
        *(float4*)hp       = make_float4(acc[0][0], acc[0][1], acc[0][2], acc[0][3]);
        *(float4*)(hp + 4) = make_float4(acc[0][4], acc[0][5], acc[0][6], acc[0][7]);
    }
    if (nb + n0 + 1 < N) {
        float* hp = H + (size_t)(nb + n0 + 1) * 64 + c0;
        *(float4*)hp       = make_float4(acc[1][0], acc[1][1], acc[1][2], acc[1][3]);
        *(float4*)(hp + 4) = make_float4(acc[1][4], acc[1][5], acc[1][6], acc[1][7]);
    }

    float pa0 = 0.f, pd0 = 0.f, pa1 = 0.f, pd1 = 0.f;
#pragma unroll
    for (int j = 0; j < 8; ++j) {
        float as = ASRC[c0 + j], ad = ADST[c0 + j];
        pa0 += acc[0][j] * as; pd0 += acc[0][j] * ad;
        pa1 += acc[1][j] * as; pd1 += acc[1][j] * ad;
    }
    pa0 += __shfl_xor(pa0, 32, 64); pd0 += __shfl_xor(pd0, 32, 64);
    pa1 += __shfl_xor(pa1, 32, 64); pd1 += __shfl_xor(pd1, 32, 64);
    if (l < 32) {
        redS[w * 64 + n0] = pa0; redS[w * 64 + n0 + 1] = pa1;
        redD[w * 64 + n0] = pd0; redD[w * 64 + n0 + 1] = pd1;
    }
    __syncthreads();
    if (tid < 64 && nb + tid < N) {
        float s = redS[tid] + redS[64 + tid] + redS[128 + tid] + redS[192 + tid];
        float d = redD[tid] + redD[64 + tid] + redD[128 + tid] + redD[192 + tid];
        AS[nb + tid] = s; AD[nb + tid] = d;
    }
}

// ---------------------------------------------------------------------------
// CSR build via two-level counting sort (all atomics in LDS, writes packed).
// ebuck entry packs (dst_local << 25) | src  (src < 2^25, dst_local < 128).
// ---------------------------------------------------------------------------
__global__ __launch_bounds__(256)
void bucket_count(const int* __restrict__ dst, int E, int nbuckp,
                  int* __restrict__ cnts) {
    __shared__ int hist[512];
    int tid = threadIdx.x;
    for (int i = tid; i < nbuckp; i += 256) hist[i] = 0;
    __syncthreads();
    int e0 = blockIdx.x * EPB;
    int e1 = min(e0 + EPB, E);
    for (int e = e0 + tid; e < e1; e += 256)
        atomicAdd(&hist[dst[e] >> BSH], 1);
    __syncthreads();
    for (int i = tid; i < nbuckp; i += 256)
        cnts[blockIdx.x * nbuckp + i] = hist[i];
}

__global__ __launch_bounds__(256)
void bucket_colscan(int* __restrict__ cnts, int nblk, int nbuckp,
                    int* __restrict__ btotal) {
    __shared__ int wsums[4];
    int b = blockIdx.x;
    int tid = threadIdx.x;
    int v = (tid < nblk) ? cnts[tid * nbuckp + b] : 0;
    int excl = block_excl_scan_256(v, tid, wsums);
    if (tid < nblk) cnts[tid * nbuckp + b] = excl;
    if (tid == nblk) btotal[b] = excl;
}

__global__ __launch_bounds__(512)
void bucket_base_scan(const int* __restrict__ btotal, int nbuck,
                      int* __restrict__ bbase) {
    __shared__ int wsums[8];
    int tid = threadIdx.x;
    int lane = tid & 63, w = tid >> 6;
    int v = (tid < nbuck) ? btotal[tid] : 0;
    int x = v;
#pragma unroll
    for (int off = 1; off < 64; off <<= 1) {
        int y = __shfl_up(x, off, 64);
        if (lane >= off) x += y;
    }
    if (lane == 63) wsums[w] = x;
    __syncthreads();
    int add = 0;
#pragma unroll
    for (int i = 0; i < 8; ++i) add += (i < w) ? wsums[i] : 0;
    int excl = x + add - v;
    if (tid <= nbuck) bbase[tid] = excl;
}

__global__ __launch_bounds__(256)
void bucket_scatter(const int* __restrict__ src, const int* __restrict__ dst,
                    int E, int nbuckp, const int* __restrict__ cnts,
                    const int* __restrict__ bbase, int* __restrict__ ebuck) {
    __shared__ int cur[512];
    int tid = threadIdx.x;
    for (int i = tid; i < nbuckp; i += 256)
        cur[i] = bbase[i] + cnts[blockIdx.x * nbuckp + i];
    __syncthreads();
    int e0 = blockIdx.x * EPB;
    int e1 = min(e0 + EPB, E);
    for (int e = e0 + tid; e < e1; e += 256) {
        int d = dst[e];
        int p = atomicAdd(&cur[d >> BSH], 1);              // LDS atomic
        ebuck[p] = ((d & (NPB - 1)) << 25) | src[e];       // packed 4B write
    }
}

__global__ __launch_bounds__(256)
void bucket_to_csr(const int* __restrict__ ebuck, const int* __restrict__ bbase,
                   int N, int E, int* __restrict__ row_ptr,
                   int* __restrict__ csr_src) {
    __shared__ int hist[NPB];
    __shared__ int cur[NPB];
    __shared__ int wsums[4];
    int b = blockIdx.x, tid = threadIdx.x;
    int nstart = b << BSH;
    int base = bbase[b], endp = bbase[b + 1];
    if (tid < NPB) hist[tid] = 0;
    __syncthreads();
    for (int e = base + tid; e < endp; e += 256)
        atomicAdd(&hist[((unsigned)ebuck[e]) >> 25], 1);
    __syncthreads();
    int v = (tid < NPB) ? hist[tid] : 0;
    int excl = block_excl_scan_256(v, tid, wsums);
    if (tid < NPB) {
        cur[tid] = excl;
        if (nstart + tid < N) row_ptr[nstart + tid] = base + excl;
    }
    if (b == 0 && tid == 0) row_ptr[N] = E;
    __syncthreads();
    for (int e = base + tid; e < endp; e += 256) {
        int pv = ebuck[e];
        int p = atomicAdd(&cur[((unsigned)pv) >> 25], 1);
        csr_src[base + p] = pv & 0x1FFFFFF;
    }
}

// ---------------------------------------------------------------------------
// Fused softmax + aggregate: one wave per dst node.
// Softmax: lane = edge (deg<=64), shfl-xor reductions.
// Accumulate: 16 lanes per edge-row (16 x float4 = 256B row), 4 edges per
// load instruction, 8 edges in flight via dual accumulators. Cross-group
// reduce via shfl_xor(16,32); lanes 0-15 write one float4 (coalesced row).
// ---------------------------------------------------------------------------
__global__ __launch_bounds__(256)
void gat_aggregate(const float* __restrict__ H, const float* __restrict__ AS,
                   const float* __restrict__ AD, const int* __restrict__ row_ptr,
                   const int* __restrict__ csr_src, const float* __restrict__ bias,
                   float* __restrict__ OUT, int N, int relu) {
    const int lane = threadIdx.x & 63;
    const int n = blockIdx.x * 4 + (threadIdx.x >> 6);
    if (n >= N) return;

    const int base = row_ptr[n], end = row_ptr[n + 1];
    const int cnt = end - base;
    const float adn = AD[n];

    if (cnt > 64) {   // rare slow path (scalar, 2-pass)
        float m = -INFINITY;
        for (int c0 = base; c0 < end; c0 += 64) {
            int c = min(64, end - c0);
            float e = -INFINITY;
            if (lane < c) {
                int sr = csr_src[c0 + lane];
                float t = AS[sr] + adn;
                e = t > 0.f ? t : 0.2f * t;
            }
#pragma unroll
            for (int off = 32; off > 0; off >>= 1) e = fmaxf(e, __shfl_xor(e, off, 64));
            m = fmaxf(m, e);
        }
        float s = 0.f, acc = 0.f;
        for (int c0 = base; c0 < end; c0 += 64) {
            int c = min(64, end - c0);
            int srcl = 0;
            float p = 0.f;
            if (lane < c) {
                srcl = csr_src[c0 + lane];
                float t = AS[srcl] + adn;
                t = t > 0.f ? t : 0.2f * t;
                p = __expf(t - m);
            }
            float cs = p;
#pragma unroll
            for (int off = 32; off > 0; off >>= 1) cs += __shfl_xor(cs, off, 64);
            s += cs;
            for (int j = 0; j < c; ++j)
                acc += __shfl(p, j, 64) * H[(size_t)__shfl(srcl, j, 64) * 64 + lane];
        }
        float o = acc * (1.f / (s + 1e-16f)) + bias[lane];
        if (relu) o = fmaxf(o, 0.f);
        OUT[(size_t)n * 64 + lane] = o;
        return;
    }

    // ---- fast path: deg <= 64 ----
    int srcl = 0;
    float el = -INFINITY;
    if (lane < cnt) {
        srcl = csr_src[base + lane];          // coalesced
        float e = AS[srcl] + adn;             // 4B gather (L2/L3-hot)
        el = e > 0.f ? e : 0.2f * e;          // LeakyReLU(0.2)
    }
    float m = el;
#pragma unroll
    for (int off = 32; off > 0; off >>= 1) m = fmaxf(m, __shfl_xor(m, off, 64));
    float p = (lane < cnt) ? __expf(el - m) : 0.f;
    float s = p;
#pragma unroll
    for (int off = 32; off > 0; off >>= 1) s += __shfl_xor(s, off, 64);
    const float inv = 1.f / (s + 1e-16f);

    const int g = lane >> 4;                  // edge group 0..3
    const int c4 = (lane & 15) * 4;           // channel base for this lane

    float4 acc0 = make_float4(0.f, 0.f, 0.f, 0.f);
    float4 acc1 = make_float4(0.f, 0.f, 0.f, 0.f);
    int j = 0;
    for (; j + 8 <= cnt; j += 8) {            // 8 edges per iter, 2 loads in flight
        int i0 = j + g, i1 = j + 4 + g;
        int s0 = __shfl(srcl, i0, 64), s1 = __shfl(srcl, i1, 64);
        float a0 = __shfl(p, i0, 64),  a1 = __shfl(p, i1, 64);
        float4 h0 = *(const float4*)(H + (size_t)s0 * 64 + c4);
        float4 h1 = *(const float4*)(H + (size_t)s1 * 64 + c4);
        acc0.x += a0 * h0.x; acc0.y += a0 * h0.y;
        acc0.z += a0 * h0.z; acc0.w += a0 * h0.w;
        acc1.x += a1 * h1.x; acc1.y += a1 * h1.y;
        acc1.z += a1 * h1.z; acc1.w += a1 * h1.w;
    }
    for (; j < cnt; j += 4) {                 // tail: alpha=0 lanes contribute 0
        int i0 = min(j + g, 63);
        int s0 = __shfl(srcl, i0, 64);
        float a0 = __shfl(p, i0, 64);
        float4 h0 = *(const float4*)(H + (size_t)s0 * 64 + c4);
        acc0.x += a0 * h0.x; acc0.y += a0 * h0.y;
        acc0.z += a0 * h0.z; acc0.w += a0 * h0.w;
    }
    acc0.x += acc1.x; acc0.y += acc1.y; acc0.z += acc1.z; acc0.w += acc1.w;
#pragma unroll
    for (int off = 16; off <= 32; off <<= 1) {
        acc0.x += __shfl_xor(acc0.x, off, 64);
        acc0.y += __shfl_xor(acc0.y, off, 64);
        acc0.z += __shfl_xor(acc0.z, off, 64);
        acc0.w += __shfl_xor(acc0.w, off, 64);
    }
    if (lane < 16) {
        float4 bv = *(const float4*)(bias + c4);
        float4 o;
        o.x = acc0.x * inv + bv.x;
        o.y = acc0.y * inv + bv.y;
        o.z = acc0.z * inv + bv.z;
        o.w = acc0.w * inv + bv.w;
        if (relu) {
            o.x = fmaxf(o.x, 0.f); o.y = fmaxf(o.y, 0.f);
            o.z = fmaxf(o.z, 0.f); o.w = fmaxf(o.w, 0.f);
        }
        *(float4*)(OUT + (size_t)n * 64 + c4) = o;
    }
}

// ---------------------------------------------------------------------------
extern "C" void kernel_launch(void* const* d_in, const int* in_sizes, int n_in,
                              void* d_out, int out_size, void* d_ws, size_t ws_size,
                              hipStream_t stream) {
    const float* x    = (const float*)d_in[0];
    const int*   ei   = (const int*)d_in[1];
    const float* W1   = (const float*)d_in[2];
    const float* as1w = (const float*)d_in[3];
    const float* ad1w = (const float*)d_in[4];
    const float* b1   = (const float*)d_in[5];
    const float* W2   = (const float*)d_in[6];
    const float* as2w = (const float*)d_in[7];
    const float* ad2w = (const float*)d_in[8];
    const float* b2   = (const float*)d_in[9];
    float* out = (float*)d_out;

    const int N = in_sizes[0] / FIN;   // 50000
    const int E = in_sizes[1] / 2;     // 800000
    const int* esrc = ei;
    const int* edst = ei + E;

    const int nbuck = (N + NPB - 1) >> BSH;      // 391 (<= 512)
    const int nbuckp = nbuck;
    const int nblk = (E + EPB - 1) / EPB;        // 196 (< 256)

    float* ws  = (float*)d_ws;
    float* h   = ws;                        // [N*64]
    float* r1  = h + (size_t)N * 64;        // [N*64]
    float* AS1 = r1 + (size_t)N * 64;       // [N]
    float* AD1 = AS1 + N;
    float* AS2 = AD1 + N;
    float* AD2 = AS2 + N;
    int* row_ptr = (int*)(AD2 + N);         // [N+1]
    int* csr     = row_ptr + N + 1;         // [E]

    // CSR-build temporaries alias h / r1 (dead once gemm_feat<128> runs)
    int* ebuck  = (int*)h;                  // [E] packed (dloc<<25)|src
    int* cnts   = (int*)r1;                 // [nblk*nbuckp]
    int* btotal = cnts + nblk * nbuckp;     // [nbuck]
    int* bbase  = btotal + nbuck;           // [nbuck+1]

    hipLaunchKernelGGL(bucket_count, dim3(nblk), dim3(256), 0, stream,
                       edst, E, nbuckp, cnts);
    hipLaunchKernelGGL(bucket_colscan, dim3(nbuck), dim3(256), 0, stream,
                       cnts, nblk, nbuckp, btotal);
    hipLaunchKernelGGL(bucket_base_scan, dim3(1), dim3(512), 0, stream,
                       btotal, nbuck, bbase);
    hipLaunchKernelGGL(bucket_scatter, dim3(nblk), dim3(256), 0, stream,
                       esrc, edst, E, nbuckp, cnts, bbase, ebuck);
    hipLaunchKernelGGL(bucket_to_csr, dim3(nbuck), dim3(256), 0, stream,
                       ebuck, bbase, N, E, row_ptr, csr);

    // Layer 1
    const int nbG = (N + 63) / 64;
    hipLaunchKernelGGL(gemm_feat<128>, dim3(nbG), dim3(256), 0, stream,
                       x, W1, as1w, ad1w, h, AS1, AD1, N);
    hipLaunchKernelGGL(gat_aggregate, dim3((N + 3) / 4), dim3(256), 0, stream,
                       h, AS1, AD1, row_ptr, csr, b1, r1, N, 1);
    // Layer 2
    hipLaunchKernelGGL(gemm_feat<64>, dim3(nbG), dim3(256), 0, stream,
                       r1, W2, as2w, ad2w, h, AS2, AD2, N);
    hipLaunchKernelGGL(gat_aggregate, dim3((N + 3) / 4), dim3(256), 0, stream,
                       h, AS2, AD2, row_ptr, csr, b2, out, N, 0);
}

// Round 5
// 208.295 us; speedup vs baseline: 1.8236x; 1.0951x over previous
//
#include <hip/hip_runtime.h>
#include <cstddef>

constexpr int FIN = 128;
constexpr int EPB = 4096;   // edges per block in bucket passes
constexpr int BSH = 7;      // bucket shift: 128 nodes per bucket
constexpr int NPB = 128;    // nodes per bucket

typedef _Float16 half4 __attribute__((ext_vector_type(4)));
typedef _Float16 half8 __attribute__((ext_vector_type(8)));

// ---------------------------------------------------------------------------
// Block-wide (256-thread) exclusive scan helper: wave shfl scan + LDS combine.
// ---------------------------------------------------------------------------
__device__ __forceinline__ int block_excl_scan_256(int v, int tid, int* wsums) {
    int lane = tid & 63, w = tid >> 6;
    int x = v;
#pragma unroll
    for (int off = 1; off < 64; off <<= 1) {
        int y = __shfl_up(x, off, 64);
        if (lane >= off) x += y;
    }
    if (lane == 63) wsums[w] = x;
    __syncthreads();
    int add = 0;
#pragma unroll
    for (int i = 0; i < 4; ++i) add += (i < w) ? wsums[i] : 0;
    return x + add - v;
}

// ---------------------------------------------------------------------------
// GEMM: Hh[N,64](fp16) = X[N,K] @ W[K,64]; fused AS/AD = H·a_src / H·a_dst
// (fp32). fp32 accumulate throughout; only the stored H is fp16.
// ---------------------------------------------------------------------------
template <int K>
__global__ __launch_bounds__(256)
void gemm_feat(const float* __restrict__ X, const float* __restrict__ W,
               const float* __restrict__ ASRC, const float* __restrict__ ADST,
               _Float16* __restrict__ Hh, float* __restrict__ AS,
               float* __restrict__ AD, int N) {
    constexpr int LDX = K + 1;
    __shared__ float Xs[64 * LDX];
    __shared__ float Ws[K * 64];
    __shared__ float redS[4 * 64];
    __shared__ float redD[4 * 64];

    const int tid = threadIdx.x;
    const int nb = blockIdx.x * 64;

    for (int idx = tid; idx < K * 64; idx += 256) Ws[idx] = W[idx];

    constexpr int QPR = K / 4;
    for (int q = tid; q < 64 * QPR; q += 256) {
        int r = q / QPR, kq = q % QPR;
        float4 v = make_float4(0.f, 0.f, 0.f, 0.f);
        if (nb + r < N) v = *(const float4*)(X + (size_t)(nb + r) * K + 4 * kq);
        float* p = Xs + r * LDX + 4 * kq;
        p[0] = v.x; p[1] = v.y; p[2] = v.z; p[3] = v.w;
    }
    __syncthreads();

    const int l = tid & 63, w = tid >> 6;
    const int n0 = 2 * (l & 31);
    const int c0 = 16 * w + 8 * (l >> 5);

    float acc[2][8];
#pragma unroll
    for (int i = 0; i < 2; ++i)
#pragma unroll
        for (int j = 0; j < 8; ++j) acc[i][j] = 0.f;

    const float* xr0 = Xs + n0 * LDX;
    const float* xr1 = xr0 + LDX;
    const float* wp = Ws + c0;

#pragma unroll 4
    for (int k = 0; k < K; ++k) {
        float4 wa = *(const float4*)(wp + k * 64);
        float4 wb = *(const float4*)(wp + k * 64 + 4);
        float x0 = xr0[k];
        float x1 = xr1[k];
        acc[0][0] += x0 * wa.x; acc[0][1] += x0 * wa.y;
        acc[0][2] += x0 * wa.z; acc[0][3] += x0 * wa.w;
        acc[0][4] += x0 * wb.x; acc[0][5] += x0 * wb.y;
        acc[0][6] += x0 * wb.z; acc[0][7] += x0 * wb.w;
        acc[1][0] += x1 * wa.x; acc[1][1] += x1 * wa.y;
        acc[1][2] += x1 * wa.z; acc[1][3] += x1 * wa.w;
        acc[1][4] += x1 * wb.x; acc[1][5] += x1 * wb.y;
        acc[1][6] += x1 * wb.z; acc[1][7] += x1 * wb.w;
    }

    if (nb + n0 < N) {
        half8 o;
#pragma unroll
        for (int j = 0; j < 8; ++j) o[j] = (_Float16)acc[0][j];
        *(half8*)(Hh + (size_t)(nb + n0) * 64 + c0) = o;   // 16B store
    }
    if (nb + n0 + 1 < N) {
        half8 o;
#pragma unroll
        for (int j = 0; j < 8; ++j) o[j] = (_Float16)acc[1][j];
        *(half8*)(Hh + (size_t)(nb + n0 + 1) * 64 + c0) = o;
    }

    float pa0 = 0.f, pd0 = 0.f, pa1 = 0.f, pd1 = 0.f;
#pragma unroll
    for (int j = 0; j < 8; ++j) {
        float as = ASRC[c0 + j], ad = ADST[c0 + j];
        pa0 += acc[0][j] * as; pd0 += acc[0][j] * ad;
        pa1 += acc[1][j] * as; pd1 += acc[1][j] * ad;
    }
    pa0 += __shfl_xor(pa0, 32, 64); pd0 += __shfl_xor(pd0, 32, 64);
    pa1 += __shfl_xor(pa1, 32, 64); pd1 += __shfl_xor(pd1, 32, 64);
    if (l < 32) {
        redS[w * 64 + n0] = pa0; redS[w * 64 + n0 + 1] = pa1;
        redD[w * 64 + n0] = pd0; redD[w * 64 + n0 + 1] = pd1;
    }
    __syncthreads();
    if (tid < 64 && nb + tid < N) {
        float s = redS[tid] + redS[64 + tid] + redS[128 + tid] + redS[192 + tid];
        float d = redD[tid] + redD[64 + tid] + redD[128 + tid] + redD[192 + tid];
        AS[nb + tid] = s; AD[nb + tid] = d;
    }
}

// ---------------------------------------------------------------------------
// CSR build via two-level counting sort (all atomics in LDS, writes packed).
// ebuck entry packs (dst_local << 25) | src  (src < 2^25, dst_local < 128).
// ---------------------------------------------------------------------------
__global__ __launch_bounds__(256)
void bucket_count(const int* __restrict__ dst, int E, int nbuckp,
                  int* __restrict__ cnts) {
    __shared__ int hist[512];
    int tid = threadIdx.x;
    for (int i = tid; i < nbuckp; i += 256) hist[i] = 0;
    __syncthreads();
    int e0 = blockIdx.x * EPB;
    int e1 = min(e0 + EPB, E);
    for (int e = e0 + tid; e < e1; e += 256)
        atomicAdd(&hist[dst[e] >> BSH], 1);
    __syncthreads();
    for (int i = tid; i < nbuckp; i += 256)
        cnts[blockIdx.x * nbuckp + i] = hist[i];
}

__global__ __launch_bounds__(256)
void bucket_colscan(int* __restrict__ cnts, int nblk, int nbuckp,
                    int* __restrict__ btotal) {
    __shared__ int wsums[4];
    int b = blockIdx.x;
    int tid = threadIdx.x;
    int v = (tid < nblk) ? cnts[tid * nbuckp + b] : 0;
    int excl = block_excl_scan_256(v, tid, wsums);
    if (tid < nblk) cnts[tid * nbuckp + b] = excl;
    if (tid == nblk) btotal[b] = excl;
}

__global__ __launch_bounds__(512)
void bucket_base_scan(const int* __restrict__ btotal, int nbuck,
                      int* __restrict__ bbase) {
    __shared__ int wsums[8];
    int tid = threadIdx.x;
    int lane = tid & 63, w = tid >> 6;
    int v = (tid < nbuck) ? btotal[tid] : 0;
    int x = v;
#pragma unroll
    for (int off = 1; off < 64; off <<= 1) {
        int y = __shfl_up(x, off, 64);
        if (lane >= off) x += y;
    }
    if (lane == 63) wsums[w] = x;
    __syncthreads();
    int add = 0;
#pragma unroll
    for (int i = 0; i < 8; ++i) add += (i < w) ? wsums[i] : 0;
    int excl = x + add - v;
    if (tid <= nbuck) bbase[tid] = excl;
}

__global__ __launch_bounds__(256)
void bucket_scatter(const int* __restrict__ src, const int* __restrict__ dst,
                    int E, int nbuckp, const int* __restrict__ cnts,
                    const int* __restrict__ bbase, int* __restrict__ ebuck) {
    __shared__ int cur[512];
    int tid = threadIdx.x;
    for (int i = tid; i < nbuckp; i += 256)
        cur[i] = bbase[i] + cnts[blockIdx.x * nbuckp + i];
    __syncthreads();
    int e0 = blockIdx.x * EPB;
    int e1 = min(e0 + EPB, E);
    for (int e = e0 + tid; e < e1; e += 256) {
        int d = dst[e];
        int p = atomicAdd(&cur[d >> BSH], 1);              // LDS atomic
        ebuck[p] = ((d & (NPB - 1)) << 25) | src[e];       // packed 4B write
    }
}

__global__ __launch_bounds__(256)
void bucket_to_csr(const int* __restrict__ ebuck, const int* __restrict__ bbase,
                   int N, int E, int* __restrict__ row_ptr,
                   int* __restrict__ csr_src) {
    __shared__ int hist[NPB];
    __shared__ int cur[NPB];
    __shared__ int wsums[4];
    int b = blockIdx.x, tid = threadIdx.x;
    int nstart = b << BSH;
    int base = bbase[b], endp = bbase[b + 1];
    if (tid < NPB) hist[tid] = 0;
    __syncthreads();
    for (int e = base + tid; e < endp; e += 256)
        atomicAdd(&hist[((unsigned)ebuck[e]) >> 25], 1);
    __syncthreads();
    int v = (tid < NPB) ? hist[tid] : 0;
    int excl = block_excl_scan_256(v, tid, wsums);
    if (tid < NPB) {
        cur[tid] = excl;
        if (nstart + tid < N) row_ptr[nstart + tid] = base + excl;
    }
    if (b == 0 && tid == 0) row_ptr[N] = E;
    __syncthreads();
    for (int e = base + tid; e < endp; e += 256) {
        int pv = ebuck[e];
        int p = atomicAdd(&cur[((unsigned)pv) >> 25], 1);
        csr_src[base + p] = pv & 0x1FFFFFF;
    }
}

// ---------------------------------------------------------------------------
// Fused softmax + aggregate: one wave per dst node; H is fp16 (half bytes).
// Softmax: lane = edge (deg<=64), shfl-xor reductions.
// Accumulate: 16 lanes per edge-row (16 x 8B half4 = 128B row), 4 edges per
// load instruction, 8 edges in flight via dual accumulators. Cross-group
// reduce via shfl_xor(16,32); lanes 0-15 write one float4 (coalesced row).
// ---------------------------------------------------------------------------
__global__ __launch_bounds__(256)
void gat_aggregate(const _Float16* __restrict__ Hh, const float* __restrict__ AS,
                   const float* __restrict__ AD, const int* __restrict__ row_ptr,
                   const int* __restrict__ csr_src, const float* __restrict__ bias,
                   float* __restrict__ OUT, int N, int relu) {
    const int lane = threadIdx.x & 63;
    const int n = blockIdx.x * 4 + (threadIdx.x >> 6);
    if (n >= N) return;

    const int base = row_ptr[n], end = row_ptr[n + 1];
    const int cnt = end - base;
    const float adn = AD[n];

    if (cnt > 64) {   // rare slow path (scalar, 2-pass)
        float m = -INFINITY;
        for (int c0 = base; c0 < end; c0 += 64) {
            int c = min(64, end - c0);
            float e = -INFINITY;
            if (lane < c) {
                int sr = csr_src[c0 + lane];
                float t = AS[sr] + adn;
                e = t > 0.f ? t : 0.2f * t;
            }
#pragma unroll
            for (int off = 32; off > 0; off >>= 1) e = fmaxf(e, __shfl_xor(e, off, 64));
            m = fmaxf(m, e);
        }
        float s = 0.f, acc = 0.f;
        for (int c0 = base; c0 < end; c0 += 64) {
            int c = min(64, end - c0);
            int srcl = 0;
            float p = 0.f;
            if (lane < c) {
                srcl = csr_src[c0 + lane];
                float t = AS[srcl] + adn;
                t = t > 0.f ? t : 0.2f * t;
                p = __expf(t - m);
            }
            float cs = p;
#pragma unroll
            for (int off = 32; off > 0; off >>= 1) cs += __shfl_xor(cs, off, 64);
            s += cs;
            for (int j = 0; j < c; ++j)
                acc += __shfl(p, j, 64) *
                       (float)Hh[(size_t)__shfl(srcl, j, 64) * 64 + lane];
        }
        float o = acc * (1.f / (s + 1e-16f)) + bias[lane];
        if (relu) o = fmaxf(o, 0.f);
        OUT[(size_t)n * 64 + lane] = o;
        return;
    }

    // ---- fast path: deg <= 64 ----
    int srcl = 0;
    float el = -INFINITY;
    if (lane < cnt) {
        srcl = csr_src[base + lane];          // coalesced
        float e = AS[srcl] + adn;             // 4B gather (L2-hot)
        el = e > 0.f ? e : 0.2f * e;          // LeakyReLU(0.2)
    }
    float m = el;
#pragma unroll
    for (int off = 32; off > 0; off >>= 1) m = fmaxf(m, __shfl_xor(m, off, 64));
    float p = (lane < cnt) ? __expf(el - m) : 0.f;
    float s = p;
#pragma unroll
    for (int off = 32; off > 0; off >>= 1) s += __shfl_xor(s, off, 64);
    const float inv = 1.f / (s + 1e-16f);

    const int g = lane >> 4;                  // edge group 0..3
    const int c4 = (lane & 15) * 4;           // channel base (4 ch/lane)

    float4 acc0 = make_float4(0.f, 0.f, 0.f, 0.f);
    float4 acc1 = make_float4(0.f, 0.f, 0.f, 0.f);
    int j = 0;
    for (; j + 8 <= cnt; j += 8) {            // 8 edges/iter, 2 loads in flight
        int i0 = j + g, i1 = j + 4 + g;
        int s0 = __shfl(srcl, i0, 64), s1 = __shfl(srcl, i1, 64);
        float a0 = __shfl(p, i0, 64),  a1 = __shfl(p, i1, 64);
        half4 h0 = *(const half4*)(Hh + (size_t)s0 * 64 + c4);   // 8B load
        half4 h1 = *(const half4*)(Hh + (size_t)s1 * 64 + c4);
        acc0.x += a0 * (float)h0[0]; acc0.y += a0 * (float)h0[1];
        acc0.z += a0 * (float)h0[2]; acc0.w += a0 * (float)h0[3];
        acc1.x += a1 * (float)h1[0]; acc1.y += a1 * (float)h1[1];
        acc1.z += a1 * (float)h1[2]; acc1.w += a1 * (float)h1[3];
    }
    for (; j < cnt; j += 4) {                 // tail: p=0 lanes contribute 0
        int i0 = min(j + g, 63);
        int s0 = __shfl(srcl, i0, 64);
        float a0 = __shfl(p, i0, 64);
        half4 h0 = *(const half4*)(Hh + (size_t)s0 * 64 + c4);
        acc0.x += a0 * (float)h0[0]; acc0.y += a0 * (float)h0[1];
        acc0.z += a0 * (float)h0[2]; acc0.w += a0 * (float)h0[3];
    }
    acc0.x += acc1.x; acc0.y += acc1.y; acc0.z += acc1.z; acc0.w += acc1.w;
#pragma unroll
    for (int off = 16; off <= 32; off <<= 1) {
        acc0.x += __shfl_xor(acc0.x, off, 64);
        acc0.y += __shfl_xor(acc0.y, off, 64);
        acc0.z += __shfl_xor(acc0.z, off, 64);
        acc0.w += __shfl_xor(acc0.w, off, 64);
    }
    if (lane < 16) {
        float4 bv = *(const float4*)(bias + c4);
        float4 o;
        o.x = acc0.x * inv + bv.x;
        o.y = acc0.y * inv + bv.y;
        o.z = acc0.z * inv + bv.z;
        o.w = acc0.w * inv + bv.w;
        if (relu) {
            o.x = fmaxf(o.x, 0.f); o.y = fmaxf(o.y, 0.f);
            o.z = fmaxf(o.z, 0.f); o.w = fmaxf(o.w, 0.f);
        }
        *(float4*)(OUT + (size_t)n * 64 + c4) = o;
    }
}

// ---------------------------------------------------------------------------
extern "C" void kernel_launch(void* const* d_in, const int* in_sizes, int n_in,
                              void* d_out, int out_size, void* d_ws, size_t ws_size,
                              hipStream_t stream) {
    const float* x    = (const float*)d_in[0];
    const int*   ei   = (const int*)d_in[1];
    const float* W1   = (const float*)d_in[2];
    const float* as1w = (const float*)d_in[3];
    const float* ad1w = (const float*)d_in[4];
    const float* b1   = (const float*)d_in[5];
    const float* W2   = (const float*)d_in[6];
    const float* as2w = (const float*)d_in[7];
    const float* ad2w = (const float*)d_in[8];
    const float* b2   = (const float*)d_in[9];
    float* out = (float*)d_out;

    const int N = in_sizes[0] / FIN;   // 50000
    const int E = in_sizes[1] / 2;     // 800000
    const int* esrc = ei;
    const int* edst = ei + E;

    const int nbuck = (N + NPB - 1) >> BSH;      // 391 (<= 512)
    const int nbuckp = nbuck;
    const int nblk = (E + EPB - 1) / EPB;        // 196 (< 256)

    float* ws  = (float*)d_ws;
    _Float16* Hh = (_Float16*)ws;           // [N*64] fp16 (12.8MB region kept)
    float* r1  = ws + (size_t)N * 64;       // [N*64] fp32
    float* AS1 = r1 + (size_t)N * 64;       // [N]
    float* AD1 = AS1 + N;
    float* AS2 = AD1 + N;
    float* AD2 = AS2 + N;
    int* row_ptr = (int*)(AD2 + N);         // [N+1]
    int* csr     = row_ptr + N + 1;         // [E]

    // CSR-build temporaries alias Hh / r1 regions (dead before gemm1)
    int* ebuck  = (int*)Hh;                 // [E] packed (dloc<<25)|src
    int* cnts   = (int*)r1;                 // [nblk*nbuckp]
    int* btotal = cnts + nblk * nbuckp;     // [nbuck]
    int* bbase  = btotal + nbuck;           // [nbuck+1]

    hipLaunchKernelGGL(bucket_count, dim3(nblk), dim3(256), 0, stream,
                       edst, E, nbuckp, cnts);
    hipLaunchKernelGGL(bucket_colscan, dim3(nbuck), dim3(256), 0, stream,
                       cnts, nblk, nbuckp, btotal);
    hipLaunchKernelGGL(bucket_base_scan, dim3(1), dim3(512), 0, stream,
                       btotal, nbuck, bbase);
    hipLaunchKernelGGL(bucket_scatter, dim3(nblk), dim3(256), 0, stream,
                       esrc, edst, E, nbuckp, cnts, bbase, ebuck);
    hipLaunchKernelGGL(bucket_to_csr, dim3(nbuck), dim3(256), 0, stream,
                       ebuck, bbase, N, E, row_ptr, csr);

    // Layer 1
    const int nbG = (N + 63) / 64;
    hipLaunchKernelGGL(gemm_feat<128>, dim3(nbG), dim3(256), 0, stream,
                       x, W1, as1w, ad1w, Hh, AS1, AD1, N);
    hipLaunchKernelGGL(gat_aggregate, dim3((N + 3) / 4), dim3(256), 0, stream,
                       Hh, AS1, AD1, row_ptr, csr, b1, r1, N, 1);
    // Layer 2
    hipLaunchKernelGGL(gemm_feat<64>, dim3(nbG), dim3(256), 0, stream,
                       r1, W2, as2w, ad2w, Hh, AS2, AD2, N);
    hipLaunchKernelGGL(gat_aggregate, dim3((N + 3) / 4), dim3(256), 0, stream,
                       Hh, AS2, AD2, row_ptr, csr, b2, out, N, 0);
}

// Round 6
// 206.878 us; speedup vs baseline: 1.8361x; 1.0069x over previous
//
#include <hip/hip_runtime.h>
#include <cstddef>

constexpr int FIN = 128;
constexpr int EPB = 4096;   // edges per block in bucket passes
constexpr int BSH = 7;      // bucket shift: 128 nodes per bucket
constexpr int NPB = 128;    // nodes per bucket

typedef _Float16 half4 __attribute__((ext_vector_type(4)));
typedef _Float16 half8 __attribute__((ext_vector_type(8)));

// ---------------------------------------------------------------------------
// Block-wide (256-thread) exclusive scan helper: wave shfl scan + LDS combine.
// ---------------------------------------------------------------------------
__device__ __forceinline__ int block_excl_scan_256(int v, int tid, int* wsums) {
    int lane = tid & 63, w = tid >> 6;
    int x = v;
#pragma unroll
    for (int off = 1; off < 64; off <<= 1) {
        int y = __shfl_up(x, off, 64);
        if (lane >= off) x += y;
    }
    if (lane == 63) wsums[w] = x;
    __syncthreads();
    int add = 0;
#pragma unroll
    for (int i = 0; i < 4; ++i) add += (i < w) ? wsums[i] : 0;
    return x + add - v;
}

// ---------------------------------------------------------------------------
// GEMM device body: Hh[N,64](fp16) = X[N,K] @ W[K,64]; fused AS/AD (fp32).
// XT = float (layer 1) or _Float16 (layer 2). fp32 accumulate throughout.
// ---------------------------------------------------------------------------
template <int K, typename XT>
__device__ __forceinline__
void gemm_body(const XT* __restrict__ X, const float* __restrict__ W,
               const float* __restrict__ ASRC, const float* __restrict__ ADST,
               _Float16* __restrict__ Hh, float* __restrict__ AS,
               float* __restrict__ AD, int N, int blk, float* Xs, float* Ws,
               float* redS, float* redD) {
    constexpr int LDX = K + 1;
    const int tid = threadIdx.x;
    const int nb = blk * 64;

    for (int idx = tid; idx < K * 64; idx += 256) Ws[idx] = W[idx];

    if constexpr (sizeof(XT) == 4) {
        constexpr int QPR = K / 4;
        for (int q = tid; q < 64 * QPR; q += 256) {
            int r = q / QPR, kq = q % QPR;
            float4 v = make_float4(0.f, 0.f, 0.f, 0.f);
            if (nb + r < N) v = *(const float4*)(X + (size_t)(nb + r) * K + 4 * kq);
            float* p = Xs + r * LDX + 4 * kq;
            p[0] = v.x; p[1] = v.y; p[2] = v.z; p[3] = v.w;
        }
    } else {
        constexpr int CPR = K / 8;
        for (int q = tid; q < 64 * CPR; q += 256) {
            int r = q / CPR, kc = q % CPR;
            half8 v = {};
            if (nb + r < N) v = *(const half8*)(X + (size_t)(nb + r) * K + 8 * kc);
            float* p = Xs + r * LDX + 8 * kc;
#pragma unroll
            for (int j = 0; j < 8; ++j) p[j] = (float)v[j];
        }
    }
    __syncthreads();

    const int l = tid & 63, w = tid >> 6;
    const int n0 = 2 * (l & 31);
    const int c0 = 16 * w + 8 * (l >> 5);

    float acc[2][8];
#pragma unroll
    for (int i = 0; i < 2; ++i)
#pragma unroll
        for (int j = 0; j < 8; ++j) acc[i][j] = 0.f;

    const float* xr0 = Xs + n0 * LDX;
    const float* xr1 = xr0 + LDX;
    const float* wp = Ws + c0;

#pragma unroll 4
    for (int k = 0; k < K; ++k) {
        float4 wa = *(const float4*)(wp + k * 64);
        float4 wb = *(const float4*)(wp + k * 64 + 4);
        float x0 = xr0[k];
        float x1 = xr1[k];
        acc[0][0] += x0 * wa.x; acc[0][1] += x0 * wa.y;
        acc[0][2] += x0 * wa.z; acc[0][3] += x0 * wa.w;
        acc[0][4] += x0 * wb.x; acc[0][5] += x0 * wb.y;
        acc[0][6] += x0 * wb.z; acc[0][7] += x0 * wb.w;
        acc[1][0] += x1 * wa.x; acc[1][1] += x1 * wa.y;
        acc[1][2] += x1 * wa.z; acc[1][3] += x1 * wa.w;
        acc[1][4] += x1 * wb.x; acc[1][5] += x1 * wb.y;
        acc[1][6] += x1 * wb.z; acc[1][7] += x1 * wb.w;
    }

    if (nb + n0 < N) {
        half8 o;
#pragma unroll
        for (int j = 0; j < 8; ++j) o[j] = (_Float16)acc[0][j];
        *(half8*)(Hh + (size_t)(nb + n0) * 64 + c0) = o;
    }
    if (nb + n0 + 1 < N) {
        half8 o;
#pragma unroll
        for (int j = 0; j < 8; ++j) o[j] = (_Float16)acc[1][j];
        *(half8*)(Hh + (size_t)(nb + n0 + 1) * 64 + c0) = o;
    }

    float pa0 = 0.f, pd0 = 0.f, pa1 = 0.f, pd1 = 0.f;
#pragma unroll
    for (int j = 0; j < 8; ++j) {
        float as = ASRC[c0 + j], ad = ADST[c0 + j];
        pa0 += acc[0][j] * as; pd0 += acc[0][j] * ad;
        pa1 += acc[1][j] * as; pd1 += acc[1][j] * ad;
    }
    pa0 += __shfl_xor(pa0, 32, 64); pd0 += __shfl_xor(pd0, 32, 64);
    pa1 += __shfl_xor(pa1, 32, 64); pd1 += __shfl_xor(pd1, 32, 64);
    if (l < 32) {
        redS[w * 64 + n0] = pa0; redS[w * 64 + n0 + 1] = pa1;
        redD[w * 64 + n0] = pd0; redD[w * 64 + n0 + 1] = pd1;
    }
    __syncthreads();
    if (tid < 64 && nb + tid < N) {
        float s = redS[tid] + redS[64 + tid] + redS[128 + tid] + redS[192 + tid];
        float d = redD[tid] + redD[64 + tid] + redD[128 + tid] + redD[192 + tid];
        AS[nb + tid] = s; AD[nb + tid] = d;
    }
}

// ---------------------------------------------------------------------------
// Fused dispatch 1: blocks [0, nblk) do bucket_count; blocks [nblk, ...) do
// gemm layer-1. Independent work, one launch, overlapped execution.
// ---------------------------------------------------------------------------
__global__ __launch_bounds__(256)
void gemm1_and_count(const float* __restrict__ X, const float* __restrict__ W,
                     const float* __restrict__ ASRC, const float* __restrict__ ADST,
                     _Float16* __restrict__ Hh, float* __restrict__ AS,
                     float* __restrict__ AD, int N,
                     const int* __restrict__ dst, int E, int nblk, int nbuckp,
                     int* __restrict__ cnts, int* __restrict__ ticket) {
    constexpr int K = FIN, LDX = K + 1;
    __shared__ float Xs[64 * LDX];          // 33 KB (reused as hist in count role)
    __shared__ float Ws[K * 64];            // 32 KB
    __shared__ float redS[4 * 64];
    __shared__ float redD[4 * 64];

    const int tid = threadIdx.x;
    if ((int)blockIdx.x < nblk) {
        int* hist = (int*)Xs;
        if (blockIdx.x == 0 && tid == 0) *ticket = 0;   // reset for colscan
        for (int i = tid; i < nbuckp; i += 256) hist[i] = 0;
        __syncthreads();
        int e0 = blockIdx.x * EPB;
        int e1 = min(e0 + EPB, E);
        for (int e = e0 + tid; e < e1; e += 256)
            atomicAdd(&hist[dst[e] >> BSH], 1);
        __syncthreads();
        for (int i = tid; i < nbuckp; i += 256)
            cnts[blockIdx.x * nbuckp + i] = hist[i];
        return;
    }
    gemm_body<K, float>(X, W, ASRC, ADST, Hh, AS, AD, N, blockIdx.x - nblk,
                        Xs, Ws, redS, redD);
}

template <int K, typename XT>
__global__ __launch_bounds__(256)
void gemm_feat(const XT* __restrict__ X, const float* __restrict__ W,
               const float* __restrict__ ASRC, const float* __restrict__ ADST,
               _Float16* __restrict__ Hh, float* __restrict__ AS,
               float* __restrict__ AD, int N) {
    constexpr int LDX = K + 1;
    __shared__ float Xs[64 * LDX];
    __shared__ float Ws[K * 64];
    __shared__ float redS[4 * 64];
    __shared__ float redD[4 * 64];
    gemm_body<K, XT>(X, W, ASRC, ADST, Hh, AS, AD, N, blockIdx.x,
                     Xs, Ws, redS, redD);
}

// ---------------------------------------------------------------------------
// Column scan of cnts + fused bucket-base scan (last-arriving block does it).
// Cross-XCD visibility: btotal published via atomicExch (device scope), read
// back via atomicAdd(p, 0); ticket orders publication.
// ---------------------------------------------------------------------------
__global__ __launch_bounds__(256)
void bucket_colscan_fused(int* __restrict__ cnts, int nblk, int nbuckp,
                          int nbuck, int E, int* __restrict__ btotal,
                          int* __restrict__ bbase, int* __restrict__ ticket) {
    __shared__ int wsums[4];
    __shared__ int ws2[4];
    __shared__ int lastflag;
    int b = blockIdx.x;
    int tid = threadIdx.x;
    int v = (tid < nblk) ? cnts[tid * nbuckp + b] : 0;
    int excl = block_excl_scan_256(v, tid, wsums);
    if (tid < nblk) cnts[tid * nbuckp + b] = excl;
    if (tid == nblk) {                       // v==0 here -> excl == column total
        atomicExch(&btotal[b], excl);        // device-scope publish
        int old = atomicAdd(ticket, 1);
        lastflag = (old == nbuck - 1);
    }
    __syncthreads();
    if (!lastflag) return;
    // last block: exclusive-scan btotal[0..nbuck) -> bbase[0..nbuck]
    int i0 = 2 * tid, i1 = 2 * tid + 1;
    int v0 = (i0 < nbuck) ? atomicAdd(&btotal[i0], 0) : 0;
    int v1 = (i1 < nbuck) ? atomicAdd(&btotal[i1], 0) : 0;
    __syncthreads();
    int e2 = block_excl_scan_256(v0 + v1, tid, ws2);
    if (i0 <= nbuck) bbase[i0] = e2;
    if (i1 <= nbuck) bbase[i1] = e2 + v0;
}

__global__ __launch_bounds__(256)
void bucket_scatter(const int* __restrict__ src, const int* __restrict__ dst,
                    int E, int nbuckp, const int* __restrict__ cnts,
                    const int* __restrict__ bbase, int* __restrict__ ebuck) {
    __shared__ int cur[512];
    int tid = threadIdx.x;
    for (int i = tid; i < nbuckp; i += 256)
        cur[i] = bbase[i] + cnts[blockIdx.x * nbuckp + i];
    __syncthreads();
    int e0 = blockIdx.x * EPB;
    int e1 = min(e0 + EPB, E);
    for (int e = e0 + tid; e < e1; e += 256) {
        int d = dst[e];
        int p = atomicAdd(&cur[d >> BSH], 1);              // LDS atomic
        ebuck[p] = ((d & (NPB - 1)) << 25) | src[e];       // packed 4B write
    }
}

__global__ __launch_bounds__(256)
void bucket_to_csr(const int* __restrict__ ebuck, const int* __restrict__ bbase,
                   int N, int E, int* __restrict__ row_ptr,
                   int* __restrict__ csr_src) {
    __shared__ int hist[NPB];
    __shared__ int cur[NPB];
    __shared__ int wsums[4];
    int b = blockIdx.x, tid = threadIdx.x;
    int nstart = b << BSH;
    int base = bbase[b], endp = bbase[b + 1];
    if (tid < NPB) hist[tid] = 0;
    __syncthreads();
    for (int e = base + tid; e < endp; e += 256)
        atomicAdd(&hist[((unsigned)ebuck[e]) >> 25], 1);
    __syncthreads();
    int v = (tid < NPB) ? hist[tid] : 0;
    int excl = block_excl_scan_256(v, tid, wsums);
    if (tid < NPB) {
        cur[tid] = excl;
        if (nstart + tid < N) row_ptr[nstart + tid] = base + excl;
    }
    if (b == 0 && tid == 0) row_ptr[N] = E;
    __syncthreads();
    for (int e = base + tid; e < endp; e += 256) {
        int pv = ebuck[e];
        int p = atomicAdd(&cur[((unsigned)pv) >> 25], 1);
        csr_src[base + p] = pv & 0x1FFFFFF;
    }
}

// ---------------------------------------------------------------------------
// Fused softmax + aggregate: one wave per dst node; H fp16; OT = output type.
// ---------------------------------------------------------------------------
template <typename OT>
__global__ __launch_bounds__(256)
void gat_aggregate(const _Float16* __restrict__ Hh, const float* __restrict__ AS,
                   const float* __restrict__ AD, const int* __restrict__ row_ptr,
                   const int* __restrict__ csr_src, const float* __restrict__ bias,
                   OT* __restrict__ OUT, int N, int relu) {
    const int lane = threadIdx.x & 63;
    const int n = blockIdx.x * 4 + (threadIdx.x >> 6);
    if (n >= N) return;

    const int base = row_ptr[n], end = row_ptr[n + 1];
    const int cnt = end - base;
    const float adn = AD[n];

    if (cnt > 64) {   // rare slow path (scalar, 2-pass)
        float m = -INFINITY;
        for (int c0 = base; c0 < end; c0 += 64) {
            int c = min(64, end - c0);
            float e = -INFINITY;
            if (lane < c) {
                int sr = csr_src[c0 + lane];
                float t = AS[sr] + adn;
                e = t > 0.f ? t : 0.2f * t;
            }
#pragma unroll
            for (int off = 32; off > 0; off >>= 1) e = fmaxf(e, __shfl_xor(e, off, 64));
            m = fmaxf(m, e);
        }
        float s = 0.f, acc = 0.f;
        for (int c0 = base; c0 < end; c0 += 64) {
            int c = min(64, end - c0);
            int srcl = 0;
            float p = 0.f;
            if (lane < c) {
                srcl = csr_src[c0 + lane];
                float t = AS[srcl] + adn;
                t = t > 0.f ? t : 0.2f * t;
                p = __expf(t - m);
            }
            float cs = p;
#pragma unroll
            for (int off = 32; off > 0; off >>= 1) cs += __shfl_xor(cs, off, 64);
            s += cs;
            for (int j = 0; j < c; ++j)
                acc += __shfl(p, j, 64) *
                       (float)Hh[(size_t)__shfl(srcl, j, 64) * 64 + lane];
        }
        float o = acc * (1.f / (s + 1e-16f)) + bias[lane];
        if (relu) o = fmaxf(o, 0.f);
        OUT[(size_t)n * 64 + lane] = (OT)o;
        return;
    }

    // ---- fast path: deg <= 64 ----
    int srcl = 0;
    float el = -INFINITY;
    if (lane < cnt) {
        srcl = csr_src[base + lane];          // coalesced
        float e = AS[srcl] + adn;             // 4B gather (L2-hot)
        el = e > 0.f ? e : 0.2f * e;          // LeakyReLU(0.2)
    }
    float m = el;
#pragma unroll
    for (int off = 32; off > 0; off >>= 1) m = fmaxf(m, __shfl_xor(m, off, 64));
    float p = (lane < cnt) ? __expf(el - m) : 0.f;
    float s = p;
#pragma unroll
    for (int off = 32; off > 0; off >>= 1) s += __shfl_xor(s, off, 64);
    const float inv = 1.f / (s + 1e-16f);

    const int g = lane >> 4;                  // edge group 0..3
    const int c4 = (lane & 15) * 4;           // channel base (4 ch/lane)

    float4 acc0 = make_float4(0.f, 0.f, 0.f, 0.f);
    float4 acc1 = make_float4(0.f, 0.f, 0.f, 0.f);
    int j = 0;
    for (; j + 8 <= cnt; j += 8) {            // 8 edges/iter, 2 loads in flight
        int i0 = j + g, i1 = j + 4 + g;
        int s0 = __shfl(srcl, i0, 64), s1 = __shfl(srcl, i1, 64);
        float a0 = __shfl(p, i0, 64),  a1 = __shfl(p, i1, 64);
        half4 h0 = *(const half4*)(Hh + (size_t)s0 * 64 + c4);   // 8B load
        half4 h1 = *(const half4*)(Hh + (size_t)s1 * 64 + c4);
        acc0.x += a0 * (float)h0[0]; acc0.y += a0 * (float)h0[1];
        acc0.z += a0 * (float)h0[2]; acc0.w += a0 * (float)h0[3];
        acc1.x += a1 * (float)h1[0]; acc1.y += a1 * (float)h1[1];
        acc1.z += a1 * (float)h1[2]; acc1.w += a1 * (float)h1[3];
    }
    for (; j < cnt; j += 4) {                 // tail: p=0 lanes contribute 0
        int i0 = min(j + g, 63);
        int s0 = __shfl(srcl, i0, 64);
        float a0 = __shfl(p, i0, 64);
        half4 h0 = *(const half4*)(Hh + (size_t)s0 * 64 + c4);
        acc0.x += a0 * (float)h0[0]; acc0.y += a0 * (float)h0[1];
        acc0.z += a0 * (float)h0[2]; acc0.w += a0 * (float)h0[3];
    }
    acc0.x += acc1.x; acc0.y += acc1.y; acc0.z += acc1.z; acc0.w += acc1.w;
#pragma unroll
    for (int off = 16; off <= 32; off <<= 1) {
        acc0.x += __shfl_xor(acc0.x, off, 64);
        acc0.y += __shfl_xor(acc0.y, off, 64);
        acc0.z += __shfl_xor(acc0.z, off, 64);
        acc0.w += __shfl_xor(acc0.w, off, 64);
    }
    if (lane < 16) {
        float4 bv = *(const float4*)(bias + c4);
        float ox = acc0.x * inv + bv.x;
        float oy = acc0.y * inv + bv.y;
        float oz = acc0.z * inv + bv.z;
        float ow = acc0.w * inv + bv.w;
        if (relu) {
            ox = fmaxf(ox, 0.f); oy = fmaxf(oy, 0.f);
            oz = fmaxf(oz, 0.f); ow = fmaxf(ow, 0.f);
        }
        if constexpr (sizeof(OT) == 2) {
            half4 o; o[0] = (_Float16)ox; o[1] = (_Float16)oy;
            o[2] = (_Float16)oz; o[3] = (_Float16)ow;
            *(half4*)((_Float16*)OUT + (size_t)n * 64 + c4) = o;
        } else {
            *(float4*)((float*)OUT + (size_t)n * 64 + c4) =
                make_float4(ox, oy, oz, ow);
        }
    }
}

// ---------------------------------------------------------------------------
extern "C" void kernel_launch(void* const* d_in, const int* in_sizes, int n_in,
                              void* d_out, int out_size, void* d_ws, size_t ws_size,
                              hipStream_t stream) {
    const float* x    = (const float*)d_in[0];
    const int*   ei   = (const int*)d_in[1];
    const float* W1   = (const float*)d_in[2];
    const float* as1w = (const float*)d_in[3];
    const float* ad1w = (const float*)d_in[4];
    const float* b1   = (const float*)d_in[5];
    const float* W2   = (const float*)d_in[6];
    const float* as2w = (const float*)d_in[7];
    const float* ad2w = (const float*)d_in[8];
    const float* b2   = (const float*)d_in[9];
    float* out = (float*)d_out;

    const int N = in_sizes[0] / FIN;   // 50000
    const int E = in_sizes[1] / 2;     // 800000
    const int* esrc = ei;
    const int* edst = ei + E;

    const int nbuck = (N + NPB - 1) >> BSH;      // 391 (<= 512)
    const int nbuckp = nbuck;
    const int nblk = (E + EPB - 1) / EPB;        // 196 (< 256)

    // Workspace layout — no aliasing (~21 MB of the provided ws)
    char* wp8 = (char*)d_ws;
    _Float16* Hh  = (_Float16*)wp8;  wp8 += (size_t)N * 64 * 2;   // fp16 H
    _Float16* R1h = (_Float16*)wp8;  wp8 += (size_t)N * 64 * 2;   // fp16 relu(l1)
    float* AS1 = (float*)wp8;        wp8 += (size_t)N * 4;
    float* AD1 = (float*)wp8;        wp8 += (size_t)N * 4;
    float* AS2 = (float*)wp8;        wp8 += (size_t)N * 4;
    float* AD2 = (float*)wp8;        wp8 += (size_t)N * 4;
    int* row_ptr = (int*)wp8;        wp8 += (size_t)(N + 1) * 4;
    int* csr     = (int*)wp8;        wp8 += (size_t)E * 4;
    int* ebuck   = (int*)wp8;        wp8 += (size_t)E * 4;
    int* cnts    = (int*)wp8;        wp8 += (size_t)nblk * nbuckp * 4;
    int* btotal  = (int*)wp8;        wp8 += (size_t)nbuck * 4;
    int* bbase   = (int*)wp8;        wp8 += (size_t)(nbuck + 1) * 4;
    int* ticket  = (int*)wp8;        wp8 += 4;

    const int nbG = (N + 63) / 64;

    // 1) fused: bucket_count (blocks 0..nblk) + gemm layer-1 (rest)
    hipLaunchKernelGGL(gemm1_and_count, dim3(nblk + nbG), dim3(256), 0, stream,
                       x, W1, as1w, ad1w, Hh, AS1, AD1, N,
                       edst, E, nblk, nbuckp, cnts, ticket);
    // 2) column scan + fused bucket-base scan (last block)
    hipLaunchKernelGGL(bucket_colscan_fused, dim3(nbuck), dim3(256), 0, stream,
                       cnts, nblk, nbuckp, nbuck, E, btotal, bbase, ticket);
    // 3) scatter into buckets
    hipLaunchKernelGGL(bucket_scatter, dim3(nblk), dim3(256), 0, stream,
                       esrc, edst, E, nbuckp, cnts, bbase, ebuck);
    // 4) bucket -> CSR
    hipLaunchKernelGGL(bucket_to_csr, dim3(nbuck), dim3(256), 0, stream,
                       ebuck, bbase, N, E, row_ptr, csr);
    // 5) aggregate layer-1 (fp16 out)
    hipLaunchKernelGGL(gat_aggregate<_Float16>, dim3((N + 3) / 4), dim3(256), 0,
                       stream, Hh, AS1, AD1, row_ptr, csr, b1, R1h, N, 1);
    // 6) gemm layer-2 (fp16 in)
    hipLaunchKernelGGL((gemm_feat<64, _Float16>), dim3(nbG), dim3(256), 0, stream,
                       R1h, W2, as2w, ad2w, Hh, AS2, AD2, N);
    // 7) aggregate layer-2 (fp32 out)
    hipLaunchKernelGGL(gat_aggregate<float>, dim3((N + 3) / 4), dim3(256), 0,
                       stream, Hh, AS2, AD2, row_ptr, csr, b2, out, N, 0);
}

// Round 7
// 191.564 us; speedup vs baseline: 1.9828x; 1.0799x over previous
//
#include <hip/hip_runtime.h>
#include <cstddef>

constexpr int FIN = 128;
constexpr int EPB = 4096;   // edges per block in bucket passes
constexpr int BSH = 7;      // bucket shift: 128 nodes per bucket
constexpr int NPB = 128;    // nodes per bucket

typedef _Float16 half4 __attribute__((ext_vector_type(4)));
typedef _Float16 half8 __attribute__((ext_vector_type(8)));
typedef float floatx4 __attribute__((ext_vector_type(4)));

// ---------------------------------------------------------------------------
// Block-wide (256-thread) exclusive scan helper: wave shfl scan + LDS combine.
// ---------------------------------------------------------------------------
__device__ __forceinline__ int block_excl_scan_256(int v, int tid, int* wsums) {
    int lane = tid & 63, w = tid >> 6;
    int x = v;
#pragma unroll
    for (int off = 1; off < 64; off <<= 1) {
        int y = __shfl_up(x, off, 64);
        if (lane >= off) x += y;
    }
    if (lane == 63) wsums[w] = x;
    __syncthreads();
    int add = 0;
#pragma unroll
    for (int i = 0; i < 4; ++i) add += (i < w) ? wsums[i] : 0;
    return x + add - v;
}

// ---------------------------------------------------------------------------
// MFMA GEMM body: Hh[N,64](fp16) = X[N,K] @ W[K,64]; fused AS/AD (fp32).
// Block = 64 nodes x 64 ch. LDS: Xh[64][K] fp16 (A), WT[64][K] fp16 (B^T,
// n-major). LDH = K+8 halves -> 16B-aligned rows, b128 frag reads 2-way
// bank alias (free). Wave w owns rows r0=w*16; 4 n-tiles of 16.
// mfma_f32_16x16x32_f16: A[m=lane&15][k=quad*8+j], B[k=quad*8+j][n=lane&15],
// D col=lane&15, row=quad*4+reg (verified layouts).
// ---------------------------------------------------------------------------
template <int K, typename XT>
__device__ __forceinline__
void gemm_mfma_body(const XT* __restrict__ X, const float* __restrict__ W,
                    const float* __restrict__ ASRC, const float* __restrict__ ADST,
                    _Float16* __restrict__ Hh, float* __restrict__ AS,
                    float* __restrict__ AD, int N, int blk,
                    _Float16* Xh, _Float16* WT) {
    constexpr int LDH = K + 8;
    const int tid = threadIdx.x;
    const int nb = blk * 64;

    // ---- stage X -> Xh (fp16) ----
    if constexpr (sizeof(XT) == 4) {
        constexpr int QPR = K / 4;
        for (int i = tid; i < 64 * QPR; i += 256) {
            int r = i / QPR, q = i % QPR;
            float4 v = make_float4(0.f, 0.f, 0.f, 0.f);
            if (nb + r < N) v = *(const float4*)(X + (size_t)(nb + r) * K + 4 * q);
            half4 h; h[0] = (_Float16)v.x; h[1] = (_Float16)v.y;
            h[2] = (_Float16)v.z; h[3] = (_Float16)v.w;
            *(half4*)(Xh + r * LDH + 4 * q) = h;
        }
    } else {
        constexpr int OPR = K / 8;
        for (int i = tid; i < 64 * OPR; i += 256) {
            int r = i / OPR, o = i % OPR;
            half8 v = {};
            if (nb + r < N) v = *(const half8*)(X + (size_t)(nb + r) * K + 8 * o);
            *(half8*)(Xh + r * LDH + 8 * o) = v;
        }
    }
    // ---- stage W -> WT (transposed, fp16): thread handles (n, 4k) ----
    for (int i = tid; i < 64 * (K / 4); i += 256) {
        int n = i & 63, kg = i >> 6;
        half4 h;
#pragma unroll
        for (int j = 0; j < 4; ++j)
            h[j] = (_Float16)W[(4 * kg + j) * 64 + n];   // coalesced across lanes
        *(half4*)(WT + n * LDH + 4 * kg) = h;
    }
    __syncthreads();

    const int l = tid & 63;
    const int r0 = (tid >> 6) * 16;          // wave's row tile
    const int n16 = l & 15, quad = l >> 4;

    floatx4 acc[4];
#pragma unroll
    for (int nt = 0; nt < 4; ++nt) acc[nt] = (floatx4){0.f, 0.f, 0.f, 0.f};

#pragma unroll
    for (int k0 = 0; k0 < K; k0 += 32) {
        half8 a = *(const half8*)(Xh + (r0 + n16) * LDH + k0 + quad * 8);
#pragma unroll
        for (int nt = 0; nt < 4; ++nt) {
            half8 b = *(const half8*)(WT + (nt * 16 + n16) * LDH + k0 + quad * 8);
            acc[nt] = __builtin_amdgcn_mfma_f32_16x16x32_f16(a, b, acc[nt], 0, 0, 0);
        }
    }

    // ---- fused AS/AD: partial dot over this lane's column, reduce over n ----
    float pa[4] = {0.f, 0.f, 0.f, 0.f}, pd[4] = {0.f, 0.f, 0.f, 0.f};
#pragma unroll
    for (int nt = 0; nt < 4; ++nt) {
        float as_v = ASRC[nt * 16 + n16], ad_v = ADST[nt * 16 + n16];
#pragma unroll
        for (int reg = 0; reg < 4; ++reg) {
            pa[reg] += acc[nt][reg] * as_v;
            pd[reg] += acc[nt][reg] * ad_v;
        }
    }
#pragma unroll
    for (int off = 1; off < 16; off <<= 1) {
#pragma unroll
        for (int reg = 0; reg < 4; ++reg) {
            pa[reg] += __shfl_xor(pa[reg], off, 64);
            pd[reg] += __shfl_xor(pd[reg], off, 64);
        }
    }
    if (n16 == 0) {
#pragma unroll
        for (int reg = 0; reg < 4; ++reg) {
            int row = nb + r0 + quad * 4 + reg;
            if (row < N) { AS[row] = pa[reg]; AD[row] = pd[reg]; }
        }
    }

    // ---- H store: wave-private LDS transpose (rows r0..r0+15) -> coalesced ----
#pragma unroll
    for (int nt = 0; nt < 4; ++nt)
#pragma unroll
        for (int reg = 0; reg < 4; ++reg)
            Xh[(r0 + quad * 4 + reg) * LDH + nt * 16 + n16] = (_Float16)acc[nt][reg];
    // wave-local: compiler inserts lgkmcnt wait before dependent reads
    {
        int r = r0 + (l >> 2);               // 16 rows, 4 lanes per row
        int o = (l & 3) * 16;                // 16 halves per lane
        if (nb + r < N) {
            half8 v0 = *(const half8*)(Xh + r * LDH + o);
            half8 v1 = *(const half8*)(Xh + r * LDH + o + 8);
            *(half8*)(Hh + (size_t)(nb + r) * 64 + o) = v0;
            *(half8*)(Hh + (size_t)(nb + r) * 64 + o + 8) = v1;
        }
    }
}

// ---------------------------------------------------------------------------
// Fused dispatch 1: blocks [0, nblk) do bucket_count; rest do gemm layer-1.
// ---------------------------------------------------------------------------
__global__ __launch_bounds__(256)
void gemm1_and_count(const float* __restrict__ X, const float* __restrict__ W,
                     const float* __restrict__ ASRC, const float* __restrict__ ADST,
                     _Float16* __restrict__ Hh, float* __restrict__ AS,
                     float* __restrict__ AD, int N,
                     const int* __restrict__ dst, int E, int nblk, int nbuckp,
                     int* __restrict__ cnts, int* __restrict__ ticket) {
    constexpr int K = FIN, LDH = K + 8;
    __shared__ _Float16 Xh[64 * LDH];
    __shared__ _Float16 WT[64 * LDH];

    const int tid = threadIdx.x;
    if ((int)blockIdx.x < nblk) {
        int* hist = (int*)Xh;
        if (blockIdx.x == 0 && tid == 0) *ticket = 0;   // reset for colscan
        for (int i = tid; i < nbuckp; i += 256) hist[i] = 0;
        __syncthreads();
        int e0 = blockIdx.x * EPB;
        int e1 = min(e0 + EPB, E);
        for (int e = e0 + tid; e < e1; e += 256)
            atomicAdd(&hist[dst[e] >> BSH], 1);
        __syncthreads();
        for (int i = tid; i < nbuckp; i += 256)
            cnts[blockIdx.x * nbuckp + i] = hist[i];
        return;
    }
    gemm_mfma_body<K, float>(X, W, ASRC, ADST, Hh, AS, AD, N,
                             blockIdx.x - nblk, Xh, WT);
}

template <int K, typename XT>
__global__ __launch_bounds__(256)
void gemm_feat(const XT* __restrict__ X, const float* __restrict__ W,
               const float* __restrict__ ASRC, const float* __restrict__ ADST,
               _Float16* __restrict__ Hh, float* __restrict__ AS,
               float* __restrict__ AD, int N) {
    constexpr int LDH = K + 8;
    __shared__ _Float16 Xh[64 * LDH];
    __shared__ _Float16 WT[64 * LDH];
    gemm_mfma_body<K, XT>(X, W, ASRC, ADST, Hh, AS, AD, N, blockIdx.x, Xh, WT);
}

// ---------------------------------------------------------------------------
// Column scan of cnts + fused bucket-base scan (last-arriving block does it).
// ---------------------------------------------------------------------------
__global__ __launch_bounds__(256)
void bucket_colscan_fused(int* __restrict__ cnts, int nblk, int nbuckp,
                          int nbuck, int E, int* __restrict__ btotal,
                          int* __restrict__ bbase, int* __restrict__ ticket) {
    __shared__ int wsums[4];
    __shared__ int ws2[4];
    __shared__ int lastflag;
    int b = blockIdx.x;
    int tid = threadIdx.x;
    int v = (tid < nblk) ? cnts[tid * nbuckp + b] : 0;
    int excl = block_excl_scan_256(v, tid, wsums);
    if (tid < nblk) cnts[tid * nbuckp + b] = excl;
    if (tid == nblk) {                       // v==0 here -> excl == column total
        atomicExch(&btotal[b], excl);        // device-scope publish
        int old = atomicAdd(ticket, 1);
        lastflag = (old == nbuck - 1);
    }
    __syncthreads();
    if (!lastflag) return;
    int i0 = 2 * tid, i1 = 2 * tid + 1;
    int v0 = (i0 < nbuck) ? atomicAdd(&btotal[i0], 0) : 0;
    int v1 = (i1 < nbuck) ? atomicAdd(&btotal[i1], 0) : 0;
    __syncthreads();
    int e2 = block_excl_scan_256(v0 + v1, tid, ws2);
    if (i0 <= nbuck) bbase[i0] = e2;
    if (i1 <= nbuck) bbase[i1] = e2 + v0;
}

__global__ __launch_bounds__(256)
void bucket_scatter(const int* __restrict__ src, const int* __restrict__ dst,
                    int E, int nbuckp, const int* __restrict__ cnts,
                    const int* __restrict__ bbase, int* __restrict__ ebuck) {
    __shared__ int cur[512];
    int tid = threadIdx.x;
    for (int i = tid; i < nbuckp; i += 256)
        cur[i] = bbase[i] + cnts[blockIdx.x * nbuckp + i];
    __syncthreads();
    int e0 = blockIdx.x * EPB;
    int e1 = min(e0 + EPB, E);
    for (int e = e0 + tid; e < e1; e += 256) {
        int d = dst[e];
        int p = atomicAdd(&cur[d >> BSH], 1);              // LDS atomic
        ebuck[p] = ((d & (NPB - 1)) << 25) | src[e];       // packed 4B write
    }
}

__global__ __launch_bounds__(256)
void bucket_to_csr(const int* __restrict__ ebuck, const int* __restrict__ bbase,
                   int N, int E, int* __restrict__ row_ptr,
                   int* __restrict__ csr_src) {
    __shared__ int hist[NPB];
    __shared__ int cur[NPB];
    __shared__ int wsums[4];
    int b = blockIdx.x, tid = threadIdx.x;
    int nstart = b << BSH;
    int base = bbase[b], endp = bbase[b + 1];
    if (tid < NPB) hist[tid] = 0;
    __syncthreads();
    for (int e = base + tid; e < endp; e += 256)
        atomicAdd(&hist[((unsigned)ebuck[e]) >> 25], 1);
    __syncthreads();
    int v = (tid < NPB) ? hist[tid] : 0;
    int excl = block_excl_scan_256(v, tid, wsums);
    if (tid < NPB) {
        cur[tid] = excl;
        if (nstart + tid < N) row_ptr[nstart + tid] = base + excl;
    }
    if (b == 0 && tid == 0) row_ptr[N] = E;
    __syncthreads();
    for (int e = base + tid; e < endp; e += 256) {
        int pv = ebuck[e];
        int p = atomicAdd(&cur[((unsigned)pv) >> 25], 1);
        csr_src[base + p] = pv & 0x1FFFFFF;
    }
}

// ---------------------------------------------------------------------------
// Fused softmax + aggregate: one wave per dst node; H fp16.
// Fast path: softmax lane=edge; then 8 lanes per edge-row (8 x half8 = 128B
// row), 8 edges per volley, 2 volleys pipelined (32 lines in flight/wave).
// Epilogue: 3-level shfl_xor reduce; lanes 0-7 write half8/float4x2.
// ---------------------------------------------------------------------------
template <typename OT>
__global__ __launch_bounds__(256)
void gat_aggregate(const _Float16* __restrict__ Hh, const float* __restrict__ AS,
                   const float* __restrict__ AD, const int* __restrict__ row_ptr,
                   const int* __restrict__ csr_src, const float* __restrict__ bias,
                   OT* __restrict__ OUT, int N, int relu) {
    const int lane = threadIdx.x & 63;
    const int n = blockIdx.x * 4 + (threadIdx.x >> 6);
    if (n >= N) return;

    const int base = row_ptr[n], end = row_ptr[n + 1];
    const int cnt = end - base;
    const float adn = AD[n];

    if (cnt > 64) {   // rare slow path (scalar, 2-pass)
        float m = -INFINITY;
        for (int c0 = base; c0 < end; c0 += 64) {
            int c = min(64, end - c0);
            float e = -INFINITY;
            if (lane < c) {
                int sr = csr_src[c0 + lane];
                float t = AS[sr] + adn;
                e = t > 0.f ? t : 0.2f * t;
            }
#pragma unroll
            for (int off = 32; off > 0; off >>= 1) e = fmaxf(e, __shfl_xor(e, off, 64));
            m = fmaxf(m, e);
        }
        float s = 0.f, acc = 0.f;
        for (int c0 = base; c0 < end; c0 += 64) {
            int c = min(64, end - c0);
            int srcl = 0;
            float p = 0.f;
            if (lane < c) {
                srcl = csr_src[c0 + lane];
                float t = AS[srcl] + adn;
                t = t > 0.f ? t : 0.2f * t;
                p = __expf(t - m);
            }
            float cs = p;
#pragma unroll
            for (int off = 32; off > 0; off >>= 1) cs += __shfl_xor(cs, off, 64);
            s += cs;
            for (int j = 0; j < c; ++j)
                acc += __shfl(p, j, 64) *
                       (float)Hh[(size_t)__shfl(srcl, j, 64) * 64 + lane];
        }
        float o = acc * (1.f / (s + 1e-16f)) + bias[lane];
        if (relu) o = fmaxf(o, 0.f);
        OUT[(size_t)n * 64 + lane] = (OT)o;
        return;
    }

    // ---- fast path: deg <= 64 ----
    int srcl = 0;
    float el = -INFINITY;
    if (lane < cnt) {
        srcl = csr_src[base + lane];          // coalesced
        float e = AS[srcl] + adn;             // 4B gather (L2-hot)
        el = e > 0.f ? e : 0.2f * e;          // LeakyReLU(0.2)
    }
    float m = el;
#pragma unroll
    for (int off = 32; off > 0; off >>= 1) m = fmaxf(m, __shfl_xor(m, off, 64));
    float p = (lane < cnt) ? __expf(el - m) : 0.f;
    float s = p;
#pragma unroll
    for (int off = 32; off > 0; off >>= 1) s += __shfl_xor(s, off, 64);
    const float inv = 1.f / (s + 1e-16f);

    const int eg = lane >> 3;                 // edge slot 0..7
    const int c8 = (lane & 7) * 8;            // channel base (8 ch/lane)

    float acc[8], acc2[8];
#pragma unroll
    for (int t = 0; t < 8; ++t) { acc[t] = 0.f; acc2[t] = 0.f; }

    int j = 0;
    for (; j + 16 <= cnt; j += 16) {          // 16 edges in flight
        int iA = j + eg, iB = j + 8 + eg;
        int sA = __shfl(srcl, iA, 64), sB = __shfl(srcl, iB, 64);
        float aA = __shfl(p, iA, 64),  aB = __shfl(p, iB, 64);
        half8 hA = *(const half8*)(Hh + (size_t)sA * 64 + c8);
        half8 hB = *(const half8*)(Hh + (size_t)sB * 64 + c8);
#pragma unroll
        for (int t = 0; t < 8; ++t) {
            acc[t]  += aA * (float)hA[t];
            acc2[t] += aB * (float)hB[t];
        }
    }
    for (; j < cnt; j += 8) {                 // tail volley (p=0 kills extras)
        int iA = j + eg;                      // <= 63 always
        int sA = __shfl(srcl, iA, 64);
        float aA = __shfl(p, iA, 64);
        half8 hA = *(const half8*)(Hh + (size_t)sA * 64 + c8);
#pragma unroll
        for (int t = 0; t < 8; ++t) acc[t] += aA * (float)hA[t];
    }
#pragma unroll
    for (int t = 0; t < 8; ++t) acc[t] += acc2[t];
#pragma unroll
    for (int off = 8; off <= 32; off <<= 1)
#pragma unroll
        for (int t = 0; t < 8; ++t) acc[t] += __shfl_xor(acc[t], off, 64);

    if (lane < 8) {
        float4 b0 = *(const float4*)(bias + c8);
        float4 b1 = *(const float4*)(bias + c8 + 4);
        float o[8];
        o[0] = acc[0] * inv + b0.x; o[1] = acc[1] * inv + b0.y;
        o[2] = acc[2] * inv + b0.z; o[3] = acc[3] * inv + b0.w;
        o[4] = acc[4] * inv + b1.x; o[5] = acc[5] * inv + b1.y;
        o[6] = acc[6] * inv + b1.z; o[7] = acc[7] * inv + b1.w;
        if (relu) {
#pragma unroll
            for (int t = 0; t < 8; ++t) o[t] = fmaxf(o[t], 0.f);
        }
        if constexpr (sizeof(OT) == 2) {
            half8 hv;
#pragma unroll
            for (int t = 0; t < 8; ++t) hv[t] = (_Float16)o[t];
            *(half8*)((_Float16*)OUT + (size_t)n * 64 + c8) = hv;
        } else {
            *(float4*)((float*)OUT + (size_t)n * 64 + c8) =
                make_float4(o[0], o[1], o[2], o[3]);
            *(float4*)((float*)OUT + (size_t)n * 64 + c8 + 4) =
                make_float4(o[4], o[5], o[6], o[7]);
        }
    }
}

// ---------------------------------------------------------------------------
extern "C" void kernel_launch(void* const* d_in, const int* in_sizes, int n_in,
                              void* d_out, int out_size, void* d_ws, size_t ws_size,
                              hipStream_t stream) {
    const float* x    = (const float*)d_in[0];
    const int*   ei   = (const int*)d_in[1];
    const float* W1   = (const float*)d_in[2];
    const float* as1w = (const float*)d_in[3];
    const float* ad1w = (const float*)d_in[4];
    const float* b1   = (const float*)d_in[5];
    const float* W2   = (const float*)d_in[6];
    const float* as2w = (const float*)d_in[7];
    const float* ad2w = (const float*)d_in[8];
    const float* b2   = (const float*)d_in[9];
    float* out = (float*)d_out;

    const int N = in_sizes[0] / FIN;   // 50000
    const int E = in_sizes[1] / 2;     // 800000
    const int* esrc = ei;
    const int* edst = ei + E;

    const int nbuck = (N + NPB - 1) >> BSH;      // 391 (<= 512)
    const int nbuckp = nbuck;
    const int nblk = (E + EPB - 1) / EPB;        // 196 (< 256)

    // Workspace layout — no aliasing (~21 MB of the provided ws)
    char* wp8 = (char*)d_ws;
    _Float16* Hh  = (_Float16*)wp8;  wp8 += (size_t)N * 64 * 2;   // fp16 H
    _Float16* R1h = (_Float16*)wp8;  wp8 += (size_t)N * 64 * 2;   // fp16 relu(l1)
    float* AS1 = (float*)wp8;        wp8 += (size_t)N * 4;
    float* AD1 = (float*)wp8;        wp8 += (size_t)N * 4;
    float* AS2 = (float*)wp8;        wp8 += (size_t)N * 4;
    float* AD2 = (float*)wp8;        wp8 += (size_t)N * 4;
    int* row_ptr = (int*)wp8;        wp8 += (size_t)(N + 1) * 4;
    int* csr     = (int*)wp8;        wp8 += (size_t)E * 4;
    int* ebuck   = (int*)wp8;        wp8 += (size_t)E * 4;
    int* cnts    = (int*)wp8;        wp8 += (size_t)nblk * nbuckp * 4;
    int* btotal  = (int*)wp8;        wp8 += (size_t)nbuck * 4;
    int* bbase   = (int*)wp8;        wp8 += (size_t)(nbuck + 1) * 4;
    int* ticket  = (int*)wp8;        wp8 += 4;

    const int nbG = (N + 63) / 64;

    // 1) fused: bucket_count (blocks 0..nblk) + MFMA gemm layer-1 (rest)
    hipLaunchKernelGGL(gemm1_and_count, dim3(nblk + nbG), dim3(256), 0, stream,
                       x, W1, as1w, ad1w, Hh, AS1, AD1, N,
                       edst, E, nblk, nbuckp, cnts, ticket);
    // 2) column scan + fused bucket-base scan (last block)
    hipLaunchKernelGGL(bucket_colscan_fused, dim3(nbuck), dim3(256), 0, stream,
                       cnts, nblk, nbuckp, nbuck, E, btotal, bbase, ticket);
    // 3) scatter into buckets
    hipLaunchKernelGGL(bucket_scatter, dim3(nblk), dim3(256), 0, stream,
                       esrc, edst, E, nbuckp, cnts, bbase, ebuck);
    // 4) bucket -> CSR
    hipLaunchKernelGGL(bucket_to_csr, dim3(nbuck), dim3(256), 0, stream,
                       ebuck, bbase, N, E, row_ptr, csr);
    // 5) aggregate layer-1 (fp16 out)
    hipLaunchKernelGGL(gat_aggregate<_Float16>, dim3((N + 3) / 4), dim3(256), 0,
                       stream, Hh, AS1, AD1, row_ptr, csr, b1, R1h, N, 1);
    // 6) MFMA gemm layer-2 (fp16 in)
    hipLaunchKernelGGL((gemm_feat<64, _Float16>), dim3(nbG), dim3(256), 0, stream,
                       R1h, W2, as2w, ad2w, Hh, AS2, AD2, N);
    // 7) aggregate layer-2 (fp32 out)
    hipLaunchKernelGGL(gat_aggregate<float>, dim3((N + 3) / 4), dim3(256), 0,
                       stream, Hh, AS2, AD2, row_ptr, csr, b2, out, N, 0);
}